// Round 5
// baseline (1154.121 us; speedup 1.0000x reference)
//
#include <hip/hip_runtime.h>
#include <hip/hip_bf16.h>

// ---------------------------------------------------------------------------
// LPGCNHyperConvAblation, round 5: bucketed 2-phase CSR build (L2-resident
// scatter windows), W_c2*W_lp fusion, fused small kernels. fp32 compute.
// ---------------------------------------------------------------------------

__device__ __forceinline__ float ldf(const void* p, int f32, long long i) {
    if (f32) return ((const float*)p)[i];
    unsigned v = ((unsigned)((const unsigned short*)p)[i]) << 16;
    return __uint_as_float(v);
}

__device__ __forceinline__ int ldi(const int* __restrict__ w, int i64, long long i, int lim) {
    int v = i64 ? w[2 * i] : w[i];
    return ((unsigned)v < (unsigned)lim) ? v : 0;
}

// --- fused dtype detection (blocks 0..10 float arrays, 11..12 index arrays) --
struct DPtrs { const void* p[13]; int n[13]; };

__global__ void detect_k(DPtrs dp, int* __restrict__ flags) {
    int b = blockIdx.x;
    __shared__ int cnt;
    if (threadIdx.x == 0) cnt = 0;
    __syncthreads();
    int c = 0;
    if (b < 11) {
        const unsigned short* u = (const unsigned short*)dp.p[b];
        int np = dp.n[b]; if (np > 2048) np = 2048;
        for (int i = threadIdx.x; i < np; i += blockDim.x) {
            unsigned e = (u[i] >> 7) & 0xFFu;
            if (e != 0u && (e < 90u || e > 160u)) c++;
        }
        atomicAdd(&cnt, c);
        __syncthreads();
        if (threadIdx.x == 0) flags[b] = (cnt * 8 > np) ? 1 : 0;
    } else {
        const int* w = (const int*)dp.p[b];
        int np = dp.n[b]; if (np > 1024) np = 1024;
        for (int i = threadIdx.x; i < np; i += blockDim.x)
            if (w[2 * i + 1] != 0) c++;
        atomicAdd(&cnt, c);
        __syncthreads();
        if (threadIdx.x == 0) flags[b] = (cnt == 0) ? 1 : 0;
    }
}

// --- fused degree counting ---------------------------------------------------
__global__ void count_all_k(const int* __restrict__ ew, const int* __restrict__ hw,
                            const int* __restrict__ FL,
                            int* __restrict__ ecnt, int* __restrict__ pcntN,
                            int* __restrict__ pcntH, int E, int P, int N, int HE) {
    long long i = (long long)blockIdx.x * blockDim.x + threadIdx.x;
    if (i < E) {
        atomicAdd(&ecnt[ldi(ew, FL[11], (long long)E + i, N)], 1);
    } else if (i - E < P) {
        long long j = i - E;
        int g = FL[12];
        atomicAdd(&pcntN[ldi(hw, g, j, N)], 1);
        atomicAdd(&pcntH[ldi(hw, g, (long long)P + j, HE)], 1);
    }
}

// --- exclusive scan over concatenated [ecnt|pcntN|pcntH], rebased ------------
#define SCAN_CHUNK 2048

__global__ void scan_part_k(const int* __restrict__ in, int* __restrict__ out,
                            int* __restrict__ bsum, int n) {
    __shared__ int sh[256];
    int b = blockIdx.x, t = threadIdx.x;
    int base = b * SCAN_CHUNK + t * 8;
    int v[8];
    int sum = 0;
#pragma unroll
    for (int j = 0; j < 8; j++) { int idx = base + j; v[j] = (idx < n) ? in[idx] : 0; sum += v[j]; }
    sh[t] = sum;
    __syncthreads();
    for (int o = 1; o < 256; o <<= 1) {
        int y = (t >= o) ? sh[t - o] : 0;
        __syncthreads();
        sh[t] += y;
        __syncthreads();
    }
    int run = sh[t] - sum;
    if (t == 255) bsum[b] = sh[255];
#pragma unroll
    for (int j = 0; j < 8; j++) { int idx = base + j; if (idx < n) out[idx] = run; run += v[j]; }
}

__global__ void scan_top_k(int* __restrict__ bsum, int nb) {
    if (threadIdx.x == 0) {
        int acc = 0;
        for (int i = 0; i < nb; i++) { int v = bsum[i]; bsum[i] = acc; acc += v; }
    }
}

// rebase: [0,N) -> -0, [N,2N) -> -E, [2N,2N+HE) -> -(E+P)
__global__ void scan_add_k(int* __restrict__ out, const int* __restrict__ bsum,
                           int n, int N, int E, int P) {
    int i = blockIdx.x * blockDim.x + threadIdx.x;
    if (i < n) {
        int base = (i < N) ? 0 : ((i < 2 * N) ? E : (E + P));
        out[i] += bsum[i / SCAN_CHUNK] - base;
    }
}

// --- bucket cursor seeding (3 CSRs x 64 buckets) -----------------------------
__global__ void seed_k(const int* __restrict__ eoff, int nE, int totE, int shE,
                       const int* __restrict__ pNoff, int nPN, int totPN, int shPN,
                       const int* __restrict__ pHoff, int nPH, int totPH, int shPH,
                       int* __restrict__ bcur) {
    int b = blockIdx.x, t = threadIdx.x;
    if (t >= 64) return;
    const int* off; int n, tot, sh; int* c;
    if (b == 0)      { off = eoff;  n = nE;  tot = totE;  sh = shE;  c = bcur; }
    else if (b == 1) { off = pNoff; n = nPN; tot = totPN; sh = shPN; c = bcur + 64; }
    else             { off = pHoff; n = nPH; tot = totPH; sh = shPH; c = bcur + 128; }
    long long s = (long long)t << sh;
    c[t] = (s < n) ? off[s] : tot;
}

// --- phase B: bin (key,val) pairs into contiguous bucket regions -------------
__global__ void bucket_k(const int* __restrict__ w, const int* __restrict__ FL, int fidx,
                         long long keyOff, long long valOff, int n, int limK, int limV,
                         int sh, int* __restrict__ bcur,
                         unsigned long long* __restrict__ pbuf) {
    __shared__ int hist[64];
    __shared__ int base[64];
    int t = threadIdx.x;
    if (t < 64) hist[t] = 0;
    __syncthreads();
    int i = blockIdx.x * blockDim.x + t;
    int k = 0, v = 0, b = 0, rank = 0;
    bool act = i < n;
    if (act) {
        int g = FL[fidx];
        k = ldi(w, g, keyOff + i, limK);
        v = ldi(w, g, valOff + i, limV);
        b = k >> sh;
        rank = atomicAdd(&hist[b], 1);
    }
    __syncthreads();
    if (t < 64) base[t] = hist[t] ? atomicAdd(&bcur[t], hist[t]) : 0;
    __syncthreads();
    if (act) pbuf[base[b] + rank] = ((unsigned long long)(unsigned)k << 32) | (unsigned)v;
}

// --- phase C: contiguous read, L2-resident windowed scatter ------------------
__global__ void scatcsr_k(const unsigned long long* __restrict__ pbuf, int n,
                          const int* __restrict__ off, int* __restrict__ cur,
                          int* __restrict__ lst) {
    int i = blockIdx.x * blockDim.x + threadIdx.x;
    if (i < n) {
        unsigned long long u = pbuf[i];
        int k = (int)(u >> 32);
        int v = (int)(u & 0xFFFFFFFFu);
        int slot = atomicAdd(&cur[k], 1);
        lst[off[k] + slot] = v;
    }
}

// --- fused norm factors ------------------------------------------------------
__global__ void norms_k(const int* __restrict__ ecnt, const int* __restrict__ pcntN,
                        const int* __restrict__ pcntH, float* __restrict__ dis,
                        float* __restrict__ Dinv, float* __restrict__ Binv, int N, int HE) {
    int i = blockIdx.x * blockDim.x + threadIdx.x;
    if (i < N) dis[i] = rsqrtf((float)(ecnt[i] + 1));
    else if (i < 2 * N) { int c = pcntN[i - N]; Dinv[i - N] = c ? (1.f / (float)c) : 0.f; }
    else if (i < 2 * N + HE) { int c = pcntH[i - 2 * N]; Binv[i - 2 * N] = c ? (1.f / (float)c) : 0.f; }
}

// --- Wlp2 = W_c2 @ W_lp,  bias2 = b_c2 @ W_lp + b_lp -------------------------
__global__ void wlp2_k(const void* Wc2, const int* fWc2, const void* Wlp, const int* fWlp,
                       const void* bc2, const int* fbc2, const void* blp, const int* fblp,
                       float* __restrict__ Wlp2, float* __restrict__ bias2, int NC) {
    int t = threadIdx.x;
    for (int e = t; e < 64 * NC; e += blockDim.x) {
        int r = e / NC, c = e % NC;
        float s = 0.f;
        for (int k = 0; k < NC; k++)
            s += ldf(Wc2, fWc2[0], r * NC + k) * ldf(Wlp, fWlp[0], k * NC + c);
        Wlp2[e] = s;
    }
    for (int c = t; c < NC; c += blockDim.x) {
        float s = ldf(blp, fblp[0], c);
        for (int k = 0; k < NC; k++)
            s += ldf(bc2, fbc2[0], k) * ldf(Wlp, fWlp[0], k * NC + c);
        bias2[c] = s;
    }
}

// --- gathers (wave per destination, lane = feature) --------------------------
__global__ void gat_n2e_k(const float* __restrict__ xw, const int* __restrict__ off,
                          const int* __restrict__ cnt, const int* __restrict__ lst,
                          const float* __restrict__ Binv, float* __restrict__ ef, int HE) {
    int w = (blockIdx.x * blockDim.x + threadIdx.x) >> 6;
    int lane = threadIdx.x & 63;
    if (w < HE) {
        int o = off[w], c = cnt[w];
        float acc = 0.f;
#pragma unroll 4
        for (int j = 0; j < c; j++) {
            int nd = lst[o + j];
            acc += xw[((long long)nd << 6) + lane];
        }
        ef[((long long)w << 6) + lane] = acc * Binv[w];
    }
}

template <bool RELU>
__global__ void gat_e2n_k(const float* __restrict__ ef, const int* __restrict__ off,
                          const int* __restrict__ cnt, const int* __restrict__ lst,
                          const float* __restrict__ Dinv, const void* __restrict__ bias,
                          const int* __restrict__ fb, float* __restrict__ out, int N) {
    int w = (blockIdx.x * blockDim.x + threadIdx.x) >> 6;
    int lane = threadIdx.x & 63;
    if (w < N) {
        int o = off[w], c = cnt[w];
        float acc = 0.f;
#pragma unroll 4
        for (int j = 0; j < c; j++) {
            int he = lst[o + j];
            acc += ef[((long long)he << 6) + lane];
        }
        float v = acc * Dinv[w] + ldf(bias, fb[0], lane);
        if (RELU) v = fmaxf(v, 0.f);
        out[((long long)w << 6) + lane] = v;
    }
}

template <bool RELU>
__global__ void gcn_gat64_k(const float* __restrict__ xw, const int* __restrict__ off,
                            const int* __restrict__ cnt, const int* __restrict__ lst,
                            const float* __restrict__ dis, const void* __restrict__ bias,
                            const int* __restrict__ fb, float* __restrict__ out, int N) {
    int w = (blockIdx.x * blockDim.x + threadIdx.x) >> 6;
    int lane = threadIdx.x & 63;
    if (w < N) {
        float dd = dis[w];
        int o = off[w], c = cnt[w];
        float acc = xw[((long long)w << 6) + lane] * dd;
#pragma unroll 4
        for (int j = 0; j < c; j++) {
            int s = lst[o + j];
            acc += xw[((long long)s << 6) + lane] * dis[s];
        }
        float v = acc * dd + ldf(bias, fb[0], lane);
        if (RELU) v = fmaxf(v, 0.f);
        out[((long long)w << 6) + lane] = v;
    }
}

// runtime-M variant for the final fused aggregation (bias2 fp32, writes d_out)
__global__ void gcn_gatM_k(const float* __restrict__ xw, const int* __restrict__ off,
                           const int* __restrict__ cnt, const int* __restrict__ lst,
                           const float* __restrict__ dis, const float* __restrict__ bias2,
                           float* __restrict__ out, int N, int M) {
    int w = (blockIdx.x * blockDim.x + threadIdx.x) >> 6;
    int lane = threadIdx.x & 63;
    if (w < N && lane < M) {
        float dd = dis[w];
        int o = off[w], c = cnt[w];
        float acc = xw[(long long)w * M + lane] * dd;
#pragma unroll 4
        for (int j = 0; j < c; j++) {
            int s = lst[o + j];
            acc += xw[(long long)s * M + lane] * dis[s];
        }
        out[(long long)w * M + lane] = acc * dd + bias2[lane];
    }
}

// --- GEMM: 64x64 tile, 256 threads, 4x4 micro-tile ---------------------------
template <bool ACCUM>
__global__ __launch_bounds__(256)
void gemm64_k(const void* __restrict__ A, const int* __restrict__ fA,
              const void* __restrict__ B, const int* __restrict__ fB, long long bOff,
              float* __restrict__ C, int NR, int K, int M) {
    const int af = fA ? fA[0] : 1;
    const int bf = fB ? fB[0] : 1;
    __shared__ float As[16][65];
    __shared__ float Bs[16][65];
    const int t = threadIdx.x;
    const int tx = t & 15, ty = t >> 4;
    const long long m0 = (long long)blockIdx.x * 64;
    float c[4][4] = {};
    for (int k0 = 0; k0 < K; k0 += 16) {
        {
            int row = t >> 2;
            int kk = (t & 3) * 4;
            long long r = m0 + row;
#pragma unroll
            for (int j = 0; j < 4; j++) {
                int k = k0 + kk + j;
                As[kk + j][row] = (r < NR && k < K) ? ldf(A, af, r * K + k) : 0.f;
            }
        }
        {
            int krow = t >> 4;
            int nn = (t & 15) * 4;
            int k = k0 + krow;
#pragma unroll
            for (int j = 0; j < 4; j++) {
                int n = nn + j;
                Bs[krow][nn + j] = (k < K && n < M) ? ldf(B, bf, bOff + (long long)k * M + n) : 0.f;
            }
        }
        __syncthreads();
#pragma unroll
        for (int k = 0; k < 16; k++) {
            float a[4], b[4];
#pragma unroll
            for (int i = 0; i < 4; i++) a[i] = As[k][ty * 4 + i];
#pragma unroll
            for (int j = 0; j < 4; j++) b[j] = Bs[k][tx * 4 + j];
#pragma unroll
            for (int i = 0; i < 4; i++)
#pragma unroll
                for (int j = 0; j < 4; j++) c[i][j] = fmaf(a[i], b[j], c[i][j]);
        }
        __syncthreads();
    }
#pragma unroll
    for (int i = 0; i < 4; i++) {
        long long r = m0 + ty * 4 + i;
        if (r < NR) {
#pragma unroll
            for (int j = 0; j < 4; j++) {
                int n = tx * 4 + j;
                if (n < M) {
                    long long o = r * M + n;
                    float v = c[i][j];
                    if constexpr (ACCUM) v += C[o];
                    C[o] = v;
                }
            }
        }
    }
}

static inline dim3 g1d(long long n, int b) { return dim3((unsigned)((n + b - 1) / b)); }
static inline int imin(int a, int b) { return a < b ? a : b; }

extern "C" void kernel_launch(void* const* d_in, const int* in_sizes, int n_in,
                              void* d_out, int out_size, void* d_ws, size_t ws_size,
                              hipStream_t stream) {
    const int N  = in_sizes[0] / 128;   // 100000
    const int E  = in_sizes[1] / 2;     // 1600000
    const int P  = in_sizes[2] / 2;     // 800000
    const int HE = 20000;
    const int NC = in_sizes[9] / 64;    // 40

    const void* x    = d_in[0];
    const int*  ew   = (const int*)d_in[1];
    const int*  hw   = (const int*)d_in[2];
    const void* W_h1 = d_in[3];
    const void* b_h1 = d_in[4];
    const void* W_h2 = d_in[5];
    const void* b_h2 = d_in[6];
    const void* W_c1 = d_in[7];
    const void* b_c1 = d_in[8];
    const void* W_c2 = d_in[9];
    const void* b_c2 = d_in[10];
    const void* W_lp = d_in[11];
    const void* b_lp = d_in[12];

    // bucket shifts: smallest sh with ceil(n/2^sh) <= 64
    int shN = 0; while (((N - 1) >> shN) >= 64) shN++;
    int shH = 0; while (((HE - 1) >> shH) >= 64) shH++;

    // ---- workspace ----
    char* wp = (char*)d_ws;
    auto allocF = [&](size_t n) { float* p = (float*)wp; wp += n * 4; return p; };
    auto allocI = [&](size_t n) { int* p = (int*)wp; wp += n * 4; return p; };
    float* A0    = allocF((size_t)N * 64);
    float* A1    = allocF((size_t)N * 64);
    float* ef    = allocF((size_t)HE * 64);
    float* dis   = allocF(N);
    float* Dinv  = allocF(N);
    float* Binv  = allocF(HE);
    float* Wlp2  = allocF((size_t)64 * NC);
    float* bias2 = allocF(NC);
    int* ecnt  = allocI(N);     // counts block (contiguous with curs for 1 memset)
    int* pcntN = allocI(N);
    int* pcntH = allocI(HE);
    int* ecur  = allocI(N);
    int* pcurN = allocI(N);
    int* pcurH = allocI(HE);
    int* eoff  = allocI(N);     // offsets block (contiguous for fused scan)
    int* poffN = allocI(N);
    int* poffH = allocI(HE);
    int* esrc  = allocI(E);
    int* pheL  = allocI(P);
    int* pniL  = allocI(P);
    int* bcur  = allocI(192);
    int* bsum  = allocI(2048);
    int* FL    = allocI(16);
    wp = (char*)(((uintptr_t)wp + 7) & ~(uintptr_t)7);
    unsigned long long* pbuf = (unsigned long long*)wp;   // max(E,P) u64

    dim3 b256(256), d1(1);

    // ---- fused dtype detection ----
    DPtrs dp;
    const void* farr[11] = {x, W_h1, b_h1, W_h2, b_h2, W_c1, b_c1, W_c2, b_c2, W_lp, b_lp};
    const int   fsz[11]  = {in_sizes[0], in_sizes[3], in_sizes[4], in_sizes[5], in_sizes[6],
                            in_sizes[7], in_sizes[8], in_sizes[9], in_sizes[10], in_sizes[11],
                            in_sizes[12]};
    for (int i = 0; i < 11; ++i) { dp.p[i] = farr[i]; dp.n[i] = fsz[i]; }
    dp.p[11] = ew; dp.n[11] = imin(E, 1024);
    dp.p[12] = hw; dp.n[12] = imin(P, 1024);
    detect_k<<<dim3(13), b256, 0, stream>>>(dp, FL);
    const int* fX   = FL + 0;
    const int* fWh1 = FL + 1,  *fbh1 = FL + 2;
    const int* fWh2 = FL + 3,  *fbh2 = FL + 4;
    const int* fWc1 = FL + 5,  *fbc1 = FL + 6;
    const int* fWc2 = FL + 7,  *fbc2 = FL + 8;
    const int* fWlp = FL + 9,  *fblp = FL + 10;

    // ---- counts (one memset covers counts+curs: 2*(2N+HE) ints) ----
    hipMemsetAsync(ecnt, 0, (size_t)2 * (2 * N + HE) * 4, stream);
    count_all_k<<<g1d((long long)E + P, 256), b256, 0, stream>>>(
        ew, hw, FL, ecnt, pcntN, pcntH, E, P, N, HE);

    // ---- fused exclusive scan over [ecnt|pcntN|pcntH] ----
    {
        int n = 2 * N + HE;
        int nb = (n + SCAN_CHUNK - 1) / SCAN_CHUNK;
        scan_part_k<<<dim3(nb), b256, 0, stream>>>(ecnt, eoff, bsum, n);
        scan_top_k<<<d1, dim3(64), 0, stream>>>(bsum, nb);
        scan_add_k<<<g1d(n, 256), b256, 0, stream>>>(eoff, bsum, n, N, E, P);
    }

    // ---- bucketed CSR builds ----
    seed_k<<<dim3(3), dim3(64), 0, stream>>>(eoff, N, E, shN,
                                             poffN, N, P, shN,
                                             poffH, HE, P, shH, bcur);
    // edges: key=dst, val=src
    bucket_k<<<g1d(E, 256), b256, 0, stream>>>(ew, FL, 11, E, 0, E, N, N, shN, bcur, pbuf);
    scatcsr_k<<<g1d(E, 256), b256, 0, stream>>>(pbuf, E, eoff, ecur, esrc);
    // pairs by node: key=node, val=hyperedge
    bucket_k<<<g1d(P, 256), b256, 0, stream>>>(hw, FL, 12, 0, P, P, N, HE, shN, bcur + 64, pbuf);
    scatcsr_k<<<g1d(P, 256), b256, 0, stream>>>(pbuf, P, poffN, pcurN, pheL);
    // pairs by hyperedge: key=hyperedge, val=node
    bucket_k<<<g1d(P, 256), b256, 0, stream>>>(hw, FL, 12, P, 0, P, HE, N, shH, bcur + 128, pbuf);
    scatcsr_k<<<g1d(P, 256), b256, 0, stream>>>(pbuf, P, poffH, pcurH, pniL);

    // ---- norms + fused tail weights ----
    norms_k<<<g1d(2 * N + HE, 256), b256, 0, stream>>>(ecnt, pcntN, pcntH, dis, Dinv, Binv, N, HE);
    wlp2_k<<<d1, b256, 0, stream>>>(W_c2, fWc2, W_lp, fWlp, b_c2, fbc2, b_lp, fblp, Wlp2, bias2, NC);

    const dim3 gemmGrid((N + 63) / 64);
    const dim3 gatN(g1d((long long)N * 64, 256));
    const dim3 gatH(g1d((long long)HE * 64, 256));

    // ---- hyperconv 1 ----
    gemm64_k<false><<<gemmGrid, b256, 0, stream>>>(x, fX, W_h1, fWh1, 0, A0, N, 128, 64);
    gat_n2e_k<<<gatH, b256, 0, stream>>>(A0, poffH, pcntH, pniL, Binv, ef, HE);
    gat_e2n_k<true><<<gatN, b256, 0, stream>>>(ef, poffN, pcntN, pheL, Dinv, b_h1, fbh1, A1, N);

    // ---- hyperconv 2 ----
    gemm64_k<false><<<gemmGrid, b256, 0, stream>>>(A1, nullptr, W_h2, fWh2, 0, A0, N, 64, 64);
    gat_n2e_k<<<gatH, b256, 0, stream>>>(A0, poffH, pcntH, pniL, Binv, ef, HE);
    gat_e2n_k<false><<<gatN, b256, 0, stream>>>(ef, poffN, pcntN, pheL, Dinv, b_h2, fbh2, A1, N);
    // A1 = x_hyper

    // ---- gcn 1 ----
    gemm64_k<false><<<gemmGrid, b256, 0, stream>>>(x, fX, W_c1, fWc1, 0, A0, N, 128, 64);
    gemm64_k<true><<<gemmGrid, b256, 0, stream>>>(A1, nullptr, W_c1, fWc1, (long long)128 * 64, A0, N, 64, 64);
    gcn_gat64_k<true><<<gatN, b256, 0, stream>>>(A0, eoff, ecnt, esrc, dis, b_c1, fbc1, A1, N);

    // ---- gcn 2 + final linear fused: out = agg(A1 @ Wlp2) + bias2 ----
    gemm64_k<false><<<gemmGrid, b256, 0, stream>>>(A1, nullptr, Wlp2, nullptr, 0, A0, N, 64, NC);
    gcn_gatM_k<<<gatN, b256, 0, stream>>>(A0, eoff, ecnt, esrc, dis, bias2, (float*)d_out, N, NC);
}

// Round 6
// 702.437 us; speedup vs baseline: 1.6430x; 1.6430x over previous
//
#include <hip/hip_runtime.h>
#include <hip/hip_bf16.h>

// ---------------------------------------------------------------------------
// LPGCNHyperConvAblation, round 6: atomic-free CSR build (LDS-histogram
// bucketing, per-bucket LDS build), float4 GEMM. fp32 compute throughout.
// ---------------------------------------------------------------------------

__device__ __forceinline__ float ldf(const void* p, int f32, long long i) {
    if (f32) return ((const float*)p)[i];
    unsigned v = ((unsigned)((const unsigned short*)p)[i]) << 16;
    return __uint_as_float(v);
}

__device__ __forceinline__ int ldi(const int* __restrict__ w, int i64, long long i, int lim) {
    int v = i64 ? w[2 * i] : w[i];
    return ((unsigned)v < (unsigned)lim) ? v : 0;
}

// --- fused dtype detection ---------------------------------------------------
struct DPtrs { const void* p[13]; int n[13]; };

__global__ void detect_k(DPtrs dp, int* __restrict__ flags) {
    int b = blockIdx.x;
    __shared__ int cnt;
    if (threadIdx.x == 0) cnt = 0;
    __syncthreads();
    int c = 0;
    if (b < 11) {
        const unsigned short* u = (const unsigned short*)dp.p[b];
        int np = dp.n[b]; if (np > 2048) np = 2048;
        for (int i = threadIdx.x; i < np; i += blockDim.x) {
            unsigned e = (u[i] >> 7) & 0xFFu;
            if (e != 0u && (e < 90u || e > 160u)) c++;
        }
        atomicAdd(&cnt, c);
        __syncthreads();
        if (threadIdx.x == 0) flags[b] = (cnt * 8 > np) ? 1 : 0;
    } else {
        const int* w = (const int*)dp.p[b];
        int np = dp.n[b]; if (np > 1024) np = 1024;
        for (int i = threadIdx.x; i < np; i += blockDim.x)
            if (w[2 * i + 1] != 0) c++;
        atomicAdd(&cnt, c);
        __syncthreads();
        if (threadIdx.x == 0) flags[b] = (cnt == 0) ? 1 : 0;
    }
}

// --- item decode: edges -> CSR0 (key=dst,val=src); pairs -> CSR1+CSR2 --------
// packed u32: (localKey << 20) | val   (val < 2^20, localKey < 2^9)
struct Item { int b1; unsigned p1; int b2; unsigned p2; };

__device__ __forceinline__ Item decode(const int* __restrict__ ew, const int* __restrict__ hw,
                                       const int* __restrict__ FL, long long i,
                                       int E, int P, int N, int HE, int shN, int shH) {
    Item it; it.b2 = -1; it.p2 = 0;
    if (i < E) {
        int g = FL[11];
        int key = ldi(ew, g, (long long)E + i, N);
        int val = ldi(ew, g, i, N);
        it.b1 = key >> shN;
        it.p1 = ((unsigned)(key & ((1 << shN) - 1)) << 20) | (unsigned)val;
    } else {
        long long j = i - E;
        int g = FL[12];
        int nd = ldi(hw, g, j, N);
        int he = ldi(hw, g, (long long)P + j, HE);
        it.b1 = 256 + (nd >> shN);
        it.p1 = ((unsigned)(nd & ((1 << shN) - 1)) << 20) | (unsigned)he;
        it.b2 = 512 + (he >> shH);
        it.p2 = ((unsigned)(he & ((1 << shH) - 1)) << 20) | (unsigned)nd;
    }
    return it;
}

// --- stage 1: bucket counting (LDS hist, few global adds) --------------------
__global__ void bucket_count_k(const int* __restrict__ ew, const int* __restrict__ hw,
                               const int* __restrict__ FL, int* __restrict__ gcnt,
                               int E, int P, int N, int HE, int shN, int shH) {
    __shared__ int hist[768];
    int t = threadIdx.x;
    for (int b = t; b < 768; b += 256) hist[b] = 0;
    __syncthreads();
    long long T = (long long)E + P;
    long long stride = (long long)gridDim.x * 256;
    for (long long i = (long long)blockIdx.x * 256 + t; i < T; i += stride) {
        Item it = decode(ew, hw, FL, i, E, P, N, HE, shN, shH);
        atomicAdd(&hist[it.b1], 1);
        if (it.b2 >= 0) atomicAdd(&hist[it.b2], 1);
    }
    __syncthreads();
    for (int b = t; b < 768; b += 256) {
        int h = hist[b];
        if (h) atomicAdd(&gcnt[b], h);
    }
}

// --- stage 2: scan bucket counts (3 independent 256-scans) -------------------
__global__ void bucket_scan_k(const int* __restrict__ gcnt, int* __restrict__ bkOff,
                              int* __restrict__ gcur, int E, int P) {
    __shared__ int sh[256];
    int t = threadIdx.x;
    long long rbase[3] = {0, (long long)E, (long long)E + P};
    for (int c = 0; c < 3; c++) {
        int v = gcnt[c * 256 + t];
        sh[t] = v;
        __syncthreads();
        for (int o = 1; o < 256; o <<= 1) {
            int y = (t >= o) ? sh[t - o] : 0;
            __syncthreads();
            sh[t] += y;
            __syncthreads();
        }
        int excl = sh[t] - v;
        bkOff[c * 256 + t] = excl;
        gcur[c * 256 + t] = (int)(rbase[c] + excl);
        __syncthreads();
    }
}

// --- stage 3: place items into bucket regions (chunked two-pass) -------------
#define PCHUNK 8192

__global__ void bucket_place_k(const int* __restrict__ ew, const int* __restrict__ hw,
                               const int* __restrict__ FL, int* __restrict__ gcur,
                               unsigned* __restrict__ pbuf,
                               int E, int P, int N, int HE, int shN, int shH) {
    __shared__ int hist[768];
    __shared__ int cur[768];
    long long T = (long long)E + P;
    long long start = (long long)blockIdx.x * PCHUNK;
    long long end = start + PCHUNK; if (end > T) end = T;
    int t = threadIdx.x;
    for (int b = t; b < 768; b += 256) hist[b] = 0;
    __syncthreads();
    for (long long i = start + t; i < end; i += 256) {
        Item it = decode(ew, hw, FL, i, E, P, N, HE, shN, shH);
        atomicAdd(&hist[it.b1], 1);
        if (it.b2 >= 0) atomicAdd(&hist[it.b2], 1);
    }
    __syncthreads();
    for (int b = t; b < 768; b += 256) {
        int h = hist[b];
        cur[b] = h ? atomicAdd(&gcur[b], h) : 0;
    }
    __syncthreads();
    for (long long i = start + t; i < end; i += 256) {
        Item it = decode(ew, hw, FL, i, E, P, N, HE, shN, shH);
        int s1 = atomicAdd(&cur[it.b1], 1);
        pbuf[s1] = it.p1;
        if (it.b2 >= 0) {
            int s2 = atomicAdd(&cur[it.b2], 1);
            pbuf[s2] = it.p2;
        }
    }
}

// --- stage 4: per-bucket CSR build (LDS atomics only) ------------------------
__global__ void build_k(const unsigned* __restrict__ pbuf,
                        const int* __restrict__ gcnt, const int* __restrict__ bkOff,
                        int* __restrict__ eoff, int* __restrict__ ecnt, int* __restrict__ esrc,
                        int* __restrict__ poffN, int* __restrict__ pcntN, int* __restrict__ pheL,
                        int* __restrict__ poffH, int* __restrict__ pcntH, int* __restrict__ pniL,
                        int E, int P, int N, int HE, int shN, int shH) {
    __shared__ int hist[512];
    __shared__ int offs[512];
    __shared__ int s2[256];
    int b = blockIdx.x, t = threadIdx.x;
    int csr = b >> 8, lb = b & 255;
    int sh    = (csr == 2) ? shH : shN;
    int nkeys = (csr == 2) ? HE : N;
    int span = 1 << sh;
    int keyBase = lb << sh;
    if (keyBase >= nkeys) return;
    int keyEnd = keyBase + span; if (keyEnd > nkeys) keyEnd = nkeys;
    int cnt = gcnt[b];
    long long rbase = (csr == 0) ? 0 : ((csr == 1) ? (long long)E : (long long)E + P);
    long long pstart = rbase + bkOff[b];
    int lstBase = bkOff[b];
    int* off  = (csr == 0) ? eoff : ((csr == 1) ? poffN : poffH);
    int* cntA = (csr == 0) ? ecnt : ((csr == 1) ? pcntN : pcntH);
    int* lst  = (csr == 0) ? esrc : ((csr == 1) ? pheL : pniL);

    for (int k = t; k < 512; k += 256) hist[k] = 0;
    __syncthreads();
    for (int i = t; i < cnt; i += 256)
        atomicAdd(&hist[pbuf[pstart + i] >> 20], 1);
    __syncthreads();
    int a0 = hist[2 * t], a1 = hist[2 * t + 1];
    s2[t] = a0 + a1;
    __syncthreads();
    for (int o = 1; o < 256; o <<= 1) {
        int y = (t >= o) ? s2[t - o] : 0;
        __syncthreads();
        s2[t] += y;
        __syncthreads();
    }
    int excl = s2[t] - (a0 + a1);
    offs[2 * t] = excl;
    offs[2 * t + 1] = excl + a0;
    __syncthreads();
    for (int k = keyBase + t; k < keyEnd; k += 256) {
        off[k]  = lstBase + offs[k - keyBase];
        cntA[k] = hist[k - keyBase];
    }
    __syncthreads();
    for (int i = t; i < cnt; i += 256) {
        unsigned u = pbuf[pstart + i];
        int lk = u >> 20;
        int slot = atomicAdd(&offs[lk], 1);
        lst[lstBase + slot] = (int)(u & 0xFFFFFu);
    }
}

// --- fused norm factors ------------------------------------------------------
__global__ void norms_k(const int* __restrict__ ecnt, const int* __restrict__ pcntN,
                        const int* __restrict__ pcntH, float* __restrict__ dis,
                        float* __restrict__ Dinv, float* __restrict__ Binv, int N, int HE) {
    int i = blockIdx.x * blockDim.x + threadIdx.x;
    if (i < N) dis[i] = rsqrtf((float)(ecnt[i] + 1));
    else if (i < 2 * N) { int c = pcntN[i - N]; Dinv[i - N] = c ? (1.f / (float)c) : 0.f; }
    else if (i < 2 * N + HE) { int c = pcntH[i - 2 * N]; Binv[i - 2 * N] = c ? (1.f / (float)c) : 0.f; }
}

// --- Wlp2 = W_c2 @ W_lp, bias2 = b_c2 @ W_lp + b_lp --------------------------
__global__ void wlp2_k(const void* Wc2, const int* fWc2, const void* Wlp, const int* fWlp,
                       const void* bc2, const int* fbc2, const void* blp, const int* fblp,
                       float* __restrict__ Wlp2, float* __restrict__ bias2, int NC) {
    int t = threadIdx.x;
    for (int e = t; e < 64 * NC; e += blockDim.x) {
        int r = e / NC, c = e % NC;
        float s = 0.f;
        for (int k = 0; k < NC; k++)
            s += ldf(Wc2, fWc2[0], r * NC + k) * ldf(Wlp, fWlp[0], k * NC + c);
        Wlp2[e] = s;
    }
    for (int c = t; c < NC; c += blockDim.x) {
        float s = ldf(blp, fblp[0], c);
        for (int k = 0; k < NC; k++)
            s += ldf(bc2, fbc2[0], k) * ldf(Wlp, fWlp[0], k * NC + c);
        bias2[c] = s;
    }
}

// --- gathers (wave per destination, lane = feature) --------------------------
__global__ void gat_n2e_k(const float* __restrict__ xw, const int* __restrict__ off,
                          const int* __restrict__ cnt, const int* __restrict__ lst,
                          const float* __restrict__ Binv, float* __restrict__ ef, int HE) {
    int w = (blockIdx.x * blockDim.x + threadIdx.x) >> 6;
    int lane = threadIdx.x & 63;
    if (w < HE) {
        int o = off[w], c = cnt[w];
        float acc = 0.f;
#pragma unroll 4
        for (int j = 0; j < c; j++) {
            int nd = lst[o + j];
            acc += xw[((long long)nd << 6) + lane];
        }
        ef[((long long)w << 6) + lane] = acc * Binv[w];
    }
}

template <bool RELU>
__global__ void gat_e2n_k(const float* __restrict__ ef, const int* __restrict__ off,
                          const int* __restrict__ cnt, const int* __restrict__ lst,
                          const float* __restrict__ Dinv, const void* __restrict__ bias,
                          const int* __restrict__ fb, float* __restrict__ out, int N) {
    int w = (blockIdx.x * blockDim.x + threadIdx.x) >> 6;
    int lane = threadIdx.x & 63;
    if (w < N) {
        int o = off[w], c = cnt[w];
        float acc = 0.f;
#pragma unroll 4
        for (int j = 0; j < c; j++) {
            int he = lst[o + j];
            acc += ef[((long long)he << 6) + lane];
        }
        float v = acc * Dinv[w] + ldf(bias, fb[0], lane);
        if (RELU) v = fmaxf(v, 0.f);
        out[((long long)w << 6) + lane] = v;
    }
}

template <bool RELU>
__global__ void gcn_gat64_k(const float* __restrict__ xw, const int* __restrict__ off,
                            const int* __restrict__ cnt, const int* __restrict__ lst,
                            const float* __restrict__ dis, const void* __restrict__ bias,
                            const int* __restrict__ fb, float* __restrict__ out, int N) {
    int w = (blockIdx.x * blockDim.x + threadIdx.x) >> 6;
    int lane = threadIdx.x & 63;
    if (w < N) {
        float dd = dis[w];
        int o = off[w], c = cnt[w];
        float acc = xw[((long long)w << 6) + lane] * dd;
#pragma unroll 4
        for (int j = 0; j < c; j++) {
            int s = lst[o + j];
            acc += xw[((long long)s << 6) + lane] * dis[s];
        }
        float v = acc * dd + ldf(bias, fb[0], lane);
        if (RELU) v = fmaxf(v, 0.f);
        out[((long long)w << 6) + lane] = v;
    }
}

__global__ void gcn_gatM_k(const float* __restrict__ xw, const int* __restrict__ off,
                           const int* __restrict__ cnt, const int* __restrict__ lst,
                           const float* __restrict__ dis, const float* __restrict__ bias2,
                           float* __restrict__ out, int N, int M) {
    int w = (blockIdx.x * blockDim.x + threadIdx.x) >> 6;
    int lane = threadIdx.x & 63;
    if (w < N && lane < M) {
        float dd = dis[w];
        int o = off[w], c = cnt[w];
        float acc = xw[(long long)w * M + lane] * dd;
#pragma unroll 4
        for (int j = 0; j < c; j++) {
            int s = lst[o + j];
            acc += xw[(long long)s * M + lane] * dis[s];
        }
        out[(long long)w * M + lane] = acc * dd + bias2[lane];
    }
}

// --- GEMM: 64x64 tile, 256 threads, 4x4 micro-tile, float4 paths -------------
// requires K % 16 == 0, M % 4 == 0 (holds: K in {128,64}, M in {64,40})
template <bool ACCUM>
__global__ __launch_bounds__(256)
void gemm64_k(const void* __restrict__ A, const int* __restrict__ fA,
              const void* __restrict__ B, const int* __restrict__ fB, long long bOff,
              float* __restrict__ C, int NR, int K, int M) {
    const int af = fA ? fA[0] : 1;
    const int bf = fB ? fB[0] : 1;
    __shared__ float As[16][68];   // [k][m], pad 68 -> 16B-aligned float4 rows
    __shared__ float Bs[16][68];   // [k][n]
    const int t = threadIdx.x;
    const int tx = t & 15, ty = t >> 4;
    const long long m0 = (long long)blockIdx.x * 64;
    float c[4][4] = {};
    for (int k0 = 0; k0 < K; k0 += 16) {
        {
            int row = t >> 2;
            int kk = (t & 3) * 4;
            long long r = m0 + row;
            float4 v = make_float4(0.f, 0.f, 0.f, 0.f);
            if (r < NR) {
                long long base = r * K + k0 + kk;
                if (af) v = *(const float4*)((const float*)A + base);
                else {
                    v.x = ldf(A, 0, base); v.y = ldf(A, 0, base + 1);
                    v.z = ldf(A, 0, base + 2); v.w = ldf(A, 0, base + 3);
                }
            }
            As[kk + 0][row] = v.x; As[kk + 1][row] = v.y;
            As[kk + 2][row] = v.z; As[kk + 3][row] = v.w;
        }
        {
            int krow = t >> 4;
            int nn = (t & 15) * 4;
            int k = k0 + krow;
            float4 v = make_float4(0.f, 0.f, 0.f, 0.f);
            if (nn < M) {
                long long base = bOff + (long long)k * M + nn;
                if (bf) v = *(const float4*)((const float*)B + base);
                else {
                    v.x = ldf(B, 0, base); v.y = ldf(B, 0, base + 1);
                    v.z = ldf(B, 0, base + 2); v.w = ldf(B, 0, base + 3);
                }
            }
            *(float4*)&Bs[krow][nn] = v;
        }
        __syncthreads();
#pragma unroll
        for (int k = 0; k < 16; k++) {
            float4 a = *(const float4*)&As[k][ty * 4];
            float4 b = *(const float4*)&Bs[k][tx * 4];
            float av[4] = {a.x, a.y, a.z, a.w};
            float bv[4] = {b.x, b.y, b.z, b.w};
#pragma unroll
            for (int i = 0; i < 4; i++)
#pragma unroll
                for (int j = 0; j < 4; j++) c[i][j] = fmaf(av[i], bv[j], c[i][j]);
        }
        __syncthreads();
    }
    int n = tx * 4;
    if (n < M) {
#pragma unroll
        for (int i = 0; i < 4; i++) {
            long long r = m0 + ty * 4 + i;
            if (r < NR) {
                long long o = r * M + n;
                float4 v = make_float4(c[i][0], c[i][1], c[i][2], c[i][3]);
                if constexpr (ACCUM) {
                    float4 old = *(const float4*)&C[o];
                    v.x += old.x; v.y += old.y; v.z += old.z; v.w += old.w;
                }
                *(float4*)&C[o] = v;
            }
        }
    }
}

static inline dim3 g1d(long long n, int b) { return dim3((unsigned)((n + b - 1) / b)); }
static inline int imin(int a, int b) { return a < b ? a : b; }

extern "C" void kernel_launch(void* const* d_in, const int* in_sizes, int n_in,
                              void* d_out, int out_size, void* d_ws, size_t ws_size,
                              hipStream_t stream) {
    const int N  = in_sizes[0] / 128;   // 100000
    const int E  = in_sizes[1] / 2;     // 1600000
    const int P  = in_sizes[2] / 2;     // 800000
    const int HE = 20000;
    const int NC = in_sizes[9] / 64;    // 40

    const void* x    = d_in[0];
    const int*  ew   = (const int*)d_in[1];
    const int*  hw   = (const int*)d_in[2];
    const void* W_h1 = d_in[3];
    const void* b_h1 = d_in[4];
    const void* W_h2 = d_in[5];
    const void* b_h2 = d_in[6];
    const void* W_c1 = d_in[7];
    const void* b_c1 = d_in[8];
    const void* W_c2 = d_in[9];
    const void* b_c2 = d_in[10];
    const void* W_lp = d_in[11];
    const void* b_lp = d_in[12];

    // bucket shifts: smallest sh with ceil(n/2^sh) <= 256  (span <= 512 here)
    int shN = 0; while (((N - 1) >> shN) >= 256) shN++;   // 9 for N=100000
    int shH = 0; while (((HE - 1) >> shH) >= 256) shH++;  // 7 for HE=20000

    // ---- workspace ----
    char* wp = (char*)d_ws;
    auto allocF = [&](size_t n) { float* p = (float*)wp; wp += n * 4; return p; };
    auto allocI = [&](size_t n) { int* p = (int*)wp; wp += n * 4; return p; };
    float* A0    = allocF((size_t)N * 64);
    float* A1    = allocF((size_t)N * 64);
    float* ef    = allocF((size_t)HE * 64);
    float* dis   = allocF(N);
    float* Dinv  = allocF(N);
    float* Binv  = allocF(HE);
    float* Wlp2  = allocF((size_t)64 * NC);
    float* bias2 = allocF(NC);
    int* ecnt  = allocI(N);
    int* pcntN = allocI(N);
    int* pcntH = allocI(HE);
    int* eoff  = allocI(N);
    int* poffN = allocI(N);
    int* poffH = allocI(HE);
    int* esrc  = allocI(E);
    int* pheL  = allocI(P);
    int* pniL  = allocI(P);
    int* gBkt  = allocI(768);   // bucket counts
    int* bkOff = allocI(768);   // per-CSR exclusive bucket offsets
    int* gcur  = allocI(768);   // pbuf append cursors
    int* FL    = allocI(16);
    unsigned* pbuf = (unsigned*)allocI((size_t)E + 2 * (size_t)P);

    dim3 b256(256), d1(1);

    // ---- dtype detection ----
    DPtrs dp;
    const void* farr[11] = {x, W_h1, b_h1, W_h2, b_h2, W_c1, b_c1, W_c2, b_c2, W_lp, b_lp};
    const int   fsz[11]  = {in_sizes[0], in_sizes[3], in_sizes[4], in_sizes[5], in_sizes[6],
                            in_sizes[7], in_sizes[8], in_sizes[9], in_sizes[10], in_sizes[11],
                            in_sizes[12]};
    for (int i = 0; i < 11; ++i) { dp.p[i] = farr[i]; dp.n[i] = fsz[i]; }
    dp.p[11] = ew; dp.n[11] = imin(E, 1024);
    dp.p[12] = hw; dp.n[12] = imin(P, 1024);
    detect_k<<<dim3(13), b256, 0, stream>>>(dp, FL);
    const int* fX   = FL + 0;
    const int* fWh1 = FL + 1,  *fbh1 = FL + 2;
    const int* fWh2 = FL + 3,  *fbh2 = FL + 4;
    const int* fWc1 = FL + 5,  *fbc1 = FL + 6;
    const int* fWc2 = FL + 7,  *fbc2 = FL + 8;
    const int* fWlp = FL + 9,  *fblp = FL + 10;

    // ---- CSR build: count -> scan -> place -> build ----
    hipMemsetAsync(gBkt, 0, 768 * 4, stream);
    bucket_count_k<<<dim3(512), b256, 0, stream>>>(ew, hw, FL, gBkt, E, P, N, HE, shN, shH);
    bucket_scan_k<<<d1, b256, 0, stream>>>(gBkt, bkOff, gcur, E, P);
    {
        long long T = (long long)E + P;
        int nChunks = (int)((T + PCHUNK - 1) / PCHUNK);
        bucket_place_k<<<dim3(nChunks), b256, 0, stream>>>(ew, hw, FL, gcur, pbuf,
                                                           E, P, N, HE, shN, shH);
    }
    build_k<<<dim3(768), b256, 0, stream>>>(pbuf, gBkt, bkOff,
                                            eoff, ecnt, esrc,
                                            poffN, pcntN, pheL,
                                            poffH, pcntH, pniL,
                                            E, P, N, HE, shN, shH);

    // ---- norms + fused tail weights ----
    norms_k<<<g1d(2 * N + HE, 256), b256, 0, stream>>>(ecnt, pcntN, pcntH, dis, Dinv, Binv, N, HE);
    wlp2_k<<<d1, b256, 0, stream>>>(W_c2, fWc2, W_lp, fWlp, b_c2, fbc2, b_lp, fblp, Wlp2, bias2, NC);

    const dim3 gemmGrid((N + 63) / 64);
    const dim3 gatN(g1d((long long)N * 64, 256));
    const dim3 gatH(g1d((long long)HE * 64, 256));

    // ---- hyperconv 1 ----
    gemm64_k<false><<<gemmGrid, b256, 0, stream>>>(x, fX, W_h1, fWh1, 0, A0, N, 128, 64);
    gat_n2e_k<<<gatH, b256, 0, stream>>>(A0, poffH, pcntH, pniL, Binv, ef, HE);
    gat_e2n_k<true><<<gatN, b256, 0, stream>>>(ef, poffN, pcntN, pheL, Dinv, b_h1, fbh1, A1, N);

    // ---- hyperconv 2 ----
    gemm64_k<false><<<gemmGrid, b256, 0, stream>>>(A1, nullptr, W_h2, fWh2, 0, A0, N, 64, 64);
    gat_n2e_k<<<gatH, b256, 0, stream>>>(A0, poffH, pcntH, pniL, Binv, ef, HE);
    gat_e2n_k<false><<<gatN, b256, 0, stream>>>(ef, poffN, pcntN, pheL, Dinv, b_h2, fbh2, A1, N);
    // A1 = x_hyper

    // ---- gcn 1 ----
    gemm64_k<false><<<gemmGrid, b256, 0, stream>>>(x, fX, W_c1, fWc1, 0, A0, N, 128, 64);
    gemm64_k<true><<<gemmGrid, b256, 0, stream>>>(A1, nullptr, W_c1, fWc1, (long long)128 * 64, A0, N, 64, 64);
    gcn_gat64_k<true><<<gatN, b256, 0, stream>>>(A0, eoff, ecnt, esrc, dis, b_c1, fbc1, A1, N);

    // ---- gcn 2 + final linear fused ----
    gemm64_k<false><<<gemmGrid, b256, 0, stream>>>(A1, nullptr, Wlp2, nullptr, 0, A0, N, 64, NC);
    gcn_gatM_k<<<gatN, b256, 0, stream>>>(A0, eoff, ecnt, esrc, dis, bias2, (float*)d_out, N, NC);
}

// Round 7
// 667.296 us; speedup vs baseline: 1.7295x; 1.0527x over previous
//
#include <hip/hip_runtime.h>
#include <hip/hip_bf16.h>

// ---------------------------------------------------------------------------
// LPGCNHyperConvAblation, round 7: float4 gathers (4 rows/wave), dis-scaling
// fused into GEMM epilogues, K=192 concat GEMM. fp32 compute throughout.
// ---------------------------------------------------------------------------

__device__ __forceinline__ float ldf(const void* p, int f32, long long i) {
    if (f32) return ((const float*)p)[i];
    unsigned v = ((unsigned)((const unsigned short*)p)[i]) << 16;
    return __uint_as_float(v);
}

__device__ __forceinline__ int ldi(const int* __restrict__ w, int i64, long long i, int lim) {
    int v = i64 ? w[2 * i] : w[i];
    return ((unsigned)v < (unsigned)lim) ? v : 0;
}

// --- fused dtype detection ---------------------------------------------------
struct DPtrs { const void* p[13]; int n[13]; };

__global__ void detect_k(DPtrs dp, int* __restrict__ flags) {
    int b = blockIdx.x;
    __shared__ int cnt;
    if (threadIdx.x == 0) cnt = 0;
    __syncthreads();
    int c = 0;
    if (b < 11) {
        const unsigned short* u = (const unsigned short*)dp.p[b];
        int np = dp.n[b]; if (np > 2048) np = 2048;
        for (int i = threadIdx.x; i < np; i += blockDim.x) {
            unsigned e = (u[i] >> 7) & 0xFFu;
            if (e != 0u && (e < 90u || e > 160u)) c++;
        }
        atomicAdd(&cnt, c);
        __syncthreads();
        if (threadIdx.x == 0) flags[b] = (cnt * 8 > np) ? 1 : 0;
    } else {
        const int* w = (const int*)dp.p[b];
        int np = dp.n[b]; if (np > 1024) np = 1024;
        for (int i = threadIdx.x; i < np; i += blockDim.x)
            if (w[2 * i + 1] != 0) c++;
        atomicAdd(&cnt, c);
        __syncthreads();
        if (threadIdx.x == 0) flags[b] = (cnt == 0) ? 1 : 0;
    }
}

// --- CSR build (round-6 atomic-free pipeline, unchanged) ---------------------
struct Item { int b1; unsigned p1; int b2; unsigned p2; };

__device__ __forceinline__ Item decode(const int* __restrict__ ew, const int* __restrict__ hw,
                                       const int* __restrict__ FL, long long i,
                                       int E, int P, int N, int HE, int shN, int shH) {
    Item it; it.b2 = -1; it.p2 = 0;
    if (i < E) {
        int g = FL[11];
        int key = ldi(ew, g, (long long)E + i, N);
        int val = ldi(ew, g, i, N);
        it.b1 = key >> shN;
        it.p1 = ((unsigned)(key & ((1 << shN) - 1)) << 20) | (unsigned)val;
    } else {
        long long j = i - E;
        int g = FL[12];
        int nd = ldi(hw, g, j, N);
        int he = ldi(hw, g, (long long)P + j, HE);
        it.b1 = 256 + (nd >> shN);
        it.p1 = ((unsigned)(nd & ((1 << shN) - 1)) << 20) | (unsigned)he;
        it.b2 = 512 + (he >> shH);
        it.p2 = ((unsigned)(he & ((1 << shH) - 1)) << 20) | (unsigned)nd;
    }
    return it;
}

__global__ void bucket_count_k(const int* __restrict__ ew, const int* __restrict__ hw,
                               const int* __restrict__ FL, int* __restrict__ gcnt,
                               int E, int P, int N, int HE, int shN, int shH) {
    __shared__ int hist[768];
    int t = threadIdx.x;
    for (int b = t; b < 768; b += 256) hist[b] = 0;
    __syncthreads();
    long long T = (long long)E + P;
    long long stride = (long long)gridDim.x * 256;
    for (long long i = (long long)blockIdx.x * 256 + t; i < T; i += stride) {
        Item it = decode(ew, hw, FL, i, E, P, N, HE, shN, shH);
        atomicAdd(&hist[it.b1], 1);
        if (it.b2 >= 0) atomicAdd(&hist[it.b2], 1);
    }
    __syncthreads();
    for (int b = t; b < 768; b += 256) {
        int h = hist[b];
        if (h) atomicAdd(&gcnt[b], h);
    }
}

__global__ void bucket_scan_k(const int* __restrict__ gcnt, int* __restrict__ bkOff,
                              int* __restrict__ gcur, int E, int P) {
    __shared__ int sh[256];
    int t = threadIdx.x;
    long long rbase[3] = {0, (long long)E, (long long)E + P};
    for (int c = 0; c < 3; c++) {
        int v = gcnt[c * 256 + t];
        sh[t] = v;
        __syncthreads();
        for (int o = 1; o < 256; o <<= 1) {
            int y = (t >= o) ? sh[t - o] : 0;
            __syncthreads();
            sh[t] += y;
            __syncthreads();
        }
        int excl = sh[t] - v;
        bkOff[c * 256 + t] = excl;
        gcur[c * 256 + t] = (int)(rbase[c] + excl);
        __syncthreads();
    }
}

#define PCHUNK 8192

__global__ void bucket_place_k(const int* __restrict__ ew, const int* __restrict__ hw,
                               const int* __restrict__ FL, int* __restrict__ gcur,
                               unsigned* __restrict__ pbuf,
                               int E, int P, int N, int HE, int shN, int shH) {
    __shared__ int hist[768];
    __shared__ int cur[768];
    long long T = (long long)E + P;
    long long start = (long long)blockIdx.x * PCHUNK;
    long long end = start + PCHUNK; if (end > T) end = T;
    int t = threadIdx.x;
    for (int b = t; b < 768; b += 256) hist[b] = 0;
    __syncthreads();
    for (long long i = start + t; i < end; i += 256) {
        Item it = decode(ew, hw, FL, i, E, P, N, HE, shN, shH);
        atomicAdd(&hist[it.b1], 1);
        if (it.b2 >= 0) atomicAdd(&hist[it.b2], 1);
    }
    __syncthreads();
    for (int b = t; b < 768; b += 256) {
        int h = hist[b];
        cur[b] = h ? atomicAdd(&gcur[b], h) : 0;
    }
    __syncthreads();
    for (long long i = start + t; i < end; i += 256) {
        Item it = decode(ew, hw, FL, i, E, P, N, HE, shN, shH);
        int s1 = atomicAdd(&cur[it.b1], 1);
        pbuf[s1] = it.p1;
        if (it.b2 >= 0) {
            int s2 = atomicAdd(&cur[it.b2], 1);
            pbuf[s2] = it.p2;
        }
    }
}

__global__ void build_k(const unsigned* __restrict__ pbuf,
                        const int* __restrict__ gcnt, const int* __restrict__ bkOff,
                        int* __restrict__ eoff, int* __restrict__ ecnt, int* __restrict__ esrc,
                        int* __restrict__ poffN, int* __restrict__ pcntN, int* __restrict__ pheL,
                        int* __restrict__ poffH, int* __restrict__ pcntH, int* __restrict__ pniL,
                        int E, int P, int N, int HE, int shN, int shH) {
    __shared__ int hist[512];
    __shared__ int offs[512];
    __shared__ int s2[256];
    int b = blockIdx.x, t = threadIdx.x;
    int csr = b >> 8, lb = b & 255;
    int sh    = (csr == 2) ? shH : shN;
    int nkeys = (csr == 2) ? HE : N;
    int span = 1 << sh;
    int keyBase = lb << sh;
    if (keyBase >= nkeys) return;
    int keyEnd = keyBase + span; if (keyEnd > nkeys) keyEnd = nkeys;
    int cnt = gcnt[b];
    long long rbase = (csr == 0) ? 0 : ((csr == 1) ? (long long)E : (long long)E + P);
    long long pstart = rbase + bkOff[b];
    int lstBase = bkOff[b];
    int* off  = (csr == 0) ? eoff : ((csr == 1) ? poffN : poffH);
    int* cntA = (csr == 0) ? ecnt : ((csr == 1) ? pcntN : pcntH);
    int* lst  = (csr == 0) ? esrc : ((csr == 1) ? pheL : pniL);

    for (int k = t; k < 512; k += 256) hist[k] = 0;
    __syncthreads();
    for (int i = t; i < cnt; i += 256)
        atomicAdd(&hist[pbuf[pstart + i] >> 20], 1);
    __syncthreads();
    int a0 = hist[2 * t], a1 = hist[2 * t + 1];
    s2[t] = a0 + a1;
    __syncthreads();
    for (int o = 1; o < 256; o <<= 1) {
        int y = (t >= o) ? s2[t - o] : 0;
        __syncthreads();
        s2[t] += y;
        __syncthreads();
    }
    int excl = s2[t] - (a0 + a1);
    offs[2 * t] = excl;
    offs[2 * t + 1] = excl + a0;
    __syncthreads();
    for (int k = keyBase + t; k < keyEnd; k += 256) {
        off[k]  = lstBase + offs[k - keyBase];
        cntA[k] = hist[k - keyBase];
    }
    __syncthreads();
    for (int i = t; i < cnt; i += 256) {
        unsigned u = pbuf[pstart + i];
        int lk = u >> 20;
        int slot = atomicAdd(&offs[lk], 1);
        lst[lstBase + slot] = (int)(u & 0xFFFFFu);
    }
}

// --- fused norm factors ------------------------------------------------------
__global__ void norms_k(const int* __restrict__ ecnt, const int* __restrict__ pcntN,
                        const int* __restrict__ pcntH, float* __restrict__ dis,
                        float* __restrict__ Dinv, float* __restrict__ Binv, int N, int HE) {
    int i = blockIdx.x * blockDim.x + threadIdx.x;
    if (i < N) dis[i] = rsqrtf((float)(ecnt[i] + 1));
    else if (i < 2 * N) { int c = pcntN[i - N]; Dinv[i - N] = c ? (1.f / (float)c) : 0.f; }
    else if (i < 2 * N + HE) { int c = pcntH[i - 2 * N]; Binv[i - 2 * N] = c ? (1.f / (float)c) : 0.f; }
}

// --- Wlp2 = W_c2 @ W_lp, bias2 = b_c2 @ W_lp + b_lp --------------------------
__global__ void wlp2_k(const void* Wc2, const int* fWc2, const void* Wlp, const int* fWlp,
                       const void* bc2, const int* fbc2, const void* blp, const int* fblp,
                       float* __restrict__ Wlp2, float* __restrict__ bias2, int NC) {
    int t = threadIdx.x;
    for (int e = t; e < 64 * NC; e += blockDim.x) {
        int r = e / NC, c = e % NC;
        float s = 0.f;
        for (int k = 0; k < NC; k++)
            s += ldf(Wc2, fWc2[0], r * NC + k) * ldf(Wlp, fWlp[0], k * NC + c);
        Wlp2[e] = s;
    }
    for (int c = t; c < NC; c += blockDim.x) {
        float s = ldf(blp, fblp[0], c);
        for (int k = 0; k < NC; k++)
            s += ldf(bc2, fbc2[0], k) * ldf(Wlp, fWlp[0], k * NC + c);
        bias2[c] = s;
    }
}

// --- float4 gathers: 4 rows per wave, 16 lanes x float4 per row (D=64) -------
// node -> hyperedge: ef[e] = Binv[e] * sum xw[n]
__global__ void gat_n2e4_k(const float4* __restrict__ xw4, const int* __restrict__ off,
                           const int* __restrict__ cnt, const int* __restrict__ lst,
                           const float* __restrict__ Binv, float4* __restrict__ ef4, int HE) {
    int idx = blockIdx.x * blockDim.x + threadIdx.x;
    int e = idx >> 4, l = idx & 15;
    if (e < HE) {
        int o = off[e], c = cnt[e];
        float4 a = make_float4(0.f, 0.f, 0.f, 0.f);
        for (int j = 0; j < c; j++) {
            float4 v = xw4[((long long)lst[o + j] << 4) + l];
            a.x += v.x; a.y += v.y; a.z += v.z; a.w += v.w;
        }
        float bi = Binv[e];
        a.x *= bi; a.y *= bi; a.z *= bi; a.w *= bi;
        ef4[((long long)e << 4) + l] = a;
    }
}

// hyperedge -> node: out[n] = Dinv[n]*sum ef[e] + bias (+relu)
template <bool RELU>
__global__ void gat_e2n4_k(const float4* __restrict__ ef4, const int* __restrict__ off,
                           const int* __restrict__ cnt, const int* __restrict__ lst,
                           const float* __restrict__ Dinv, const void* __restrict__ bias,
                           const int* __restrict__ fb, float4* __restrict__ out4, int N) {
    int idx = blockIdx.x * blockDim.x + threadIdx.x;
    int w = idx >> 4, l = idx & 15;
    if (w < N) {
        int o = off[w], c = cnt[w];
        float4 a = make_float4(0.f, 0.f, 0.f, 0.f);
        for (int j = 0; j < c; j++) {
            float4 v = ef4[((long long)lst[o + j] << 4) + l];
            a.x += v.x; a.y += v.y; a.z += v.z; a.w += v.w;
        }
        float di = Dinv[w];
        int fbv = fb[0];
        float4 b = make_float4(ldf(bias, fbv, 4 * l), ldf(bias, fbv, 4 * l + 1),
                               ldf(bias, fbv, 4 * l + 2), ldf(bias, fbv, 4 * l + 3));
        a.x = a.x * di + b.x; a.y = a.y * di + b.y;
        a.z = a.z * di + b.z; a.w = a.w * di + b.w;
        if (RELU) {
            a.x = fmaxf(a.x, 0.f); a.y = fmaxf(a.y, 0.f);
            a.z = fmaxf(a.z, 0.f); a.w = fmaxf(a.w, 0.f);
        }
        out4[((long long)w << 4) + l] = a;
    }
}

// GCN aggregation on pre-scaled y (y=xw*dis): out[d] = dis[d]*(y[d]+sum y[s]) + b
template <bool RELU>
__global__ void gcn_gat4_k(const float4* __restrict__ y4, const int* __restrict__ off,
                           const int* __restrict__ cnt, const int* __restrict__ lst,
                           const float* __restrict__ dis, const void* __restrict__ bias,
                           const int* __restrict__ fb, float4* __restrict__ out4, int N) {
    int idx = blockIdx.x * blockDim.x + threadIdx.x;
    int w = idx >> 4, l = idx & 15;
    if (w < N) {
        int o = off[w], c = cnt[w];
        float4 a = y4[((long long)w << 4) + l];   // self term (= xw[d]*dis[d])
        for (int j = 0; j < c; j++) {
            float4 v = y4[((long long)lst[o + j] << 4) + l];
            a.x += v.x; a.y += v.y; a.z += v.z; a.w += v.w;
        }
        float dd = dis[w];
        int fbv = fb[0];
        float4 b = make_float4(ldf(bias, fbv, 4 * l), ldf(bias, fbv, 4 * l + 1),
                               ldf(bias, fbv, 4 * l + 2), ldf(bias, fbv, 4 * l + 3));
        a.x = a.x * dd + b.x; a.y = a.y * dd + b.y;
        a.z = a.z * dd + b.z; a.w = a.w * dd + b.w;
        if (RELU) {
            a.x = fmaxf(a.x, 0.f); a.y = fmaxf(a.y, 0.f);
            a.z = fmaxf(a.z, 0.f); a.w = fmaxf(a.w, 0.f);
        }
        out4[((long long)w << 4) + l] = a;
    }
}

// final GCN aggregation, M=NC floats (nc4=NC/4 float4 lanes), writes d_out
__global__ void gcn_gatM4_k(const float4* __restrict__ y4, const int* __restrict__ off,
                            const int* __restrict__ cnt, const int* __restrict__ lst,
                            const float* __restrict__ dis, const float* __restrict__ bias2,
                            float4* __restrict__ out4, int N, int nc4, int npw) {
    int idx = blockIdx.x * blockDim.x + threadIdx.x;
    int wave = idx >> 6, l64 = idx & 63;
    int grp = l64 / 10, li = l64 - grp * 10;   // nc4=10 hardcoded divisor path
    if (nc4 != 10) { grp = l64 / nc4; li = l64 - grp * nc4; }
    int w = wave * npw + grp;
    if (grp < npw && w < N) {
        int o = off[w], c = cnt[w];
        float4 a = y4[(long long)w * nc4 + li];  // self term
        for (int j = 0; j < c; j++) {
            float4 v = y4[(long long)lst[o + j] * nc4 + li];
            a.x += v.x; a.y += v.y; a.z += v.z; a.w += v.w;
        }
        float dd = dis[w];
        float4 b = *(const float4*)&bias2[4 * li];
        a.x = a.x * dd + b.x; a.y = a.y * dd + b.y;
        a.z = a.z * dd + b.z; a.w = a.w * dd + b.w;
        out4[(long long)w * nc4 + li] = a;
    }
}

// --- GEMM: 64x64 tile, 256 threads, 4x4 micro-tile, float4, opt. row scale ---
template <bool SCALE>
__global__ __launch_bounds__(256)
void gemm64_k(const void* __restrict__ A, const int* __restrict__ fA,
              const void* __restrict__ B, const int* __restrict__ fB,
              const float* __restrict__ dscale,
              float* __restrict__ C, int NR, int K, int M) {
    const int af = fA ? fA[0] : 1;
    const int bf = fB ? fB[0] : 1;
    __shared__ float As[16][68];
    __shared__ float Bs[16][68];
    const int t = threadIdx.x;
    const int tx = t & 15, ty = t >> 4;
    const long long m0 = (long long)blockIdx.x * 64;
    float c[4][4] = {};
    for (int k0 = 0; k0 < K; k0 += 16) {
        {
            int row = t >> 2;
            int kk = (t & 3) * 4;
            long long r = m0 + row;
            float4 v = make_float4(0.f, 0.f, 0.f, 0.f);
            if (r < NR) {
                long long base = r * K + k0 + kk;
                if (af) v = *(const float4*)((const float*)A + base);
                else {
                    v.x = ldf(A, 0, base); v.y = ldf(A, 0, base + 1);
                    v.z = ldf(A, 0, base + 2); v.w = ldf(A, 0, base + 3);
                }
            }
            As[kk + 0][row] = v.x; As[kk + 1][row] = v.y;
            As[kk + 2][row] = v.z; As[kk + 3][row] = v.w;
        }
        {
            int krow = t >> 4;
            int nn = (t & 15) * 4;
            int k = k0 + krow;
            float4 v = make_float4(0.f, 0.f, 0.f, 0.f);
            if (nn < M) {
                long long base = (long long)k * M + nn;
                if (bf) v = *(const float4*)((const float*)B + base);
                else {
                    v.x = ldf(B, 0, base); v.y = ldf(B, 0, base + 1);
                    v.z = ldf(B, 0, base + 2); v.w = ldf(B, 0, base + 3);
                }
            }
            *(float4*)&Bs[krow][nn] = v;
        }
        __syncthreads();
#pragma unroll
        for (int k = 0; k < 16; k++) {
            float4 a = *(const float4*)&As[k][ty * 4];
            float4 b = *(const float4*)&Bs[k][tx * 4];
            float av[4] = {a.x, a.y, a.z, a.w};
            float bv[4] = {b.x, b.y, b.z, b.w};
#pragma unroll
            for (int i = 0; i < 4; i++)
#pragma unroll
                for (int j = 0; j < 4; j++) c[i][j] = fmaf(av[i], bv[j], c[i][j]);
        }
        __syncthreads();
    }
    int n = tx * 4;
    if (n < M) {
#pragma unroll
        for (int i = 0; i < 4; i++) {
            long long r = m0 + ty * 4 + i;
            if (r < NR) {
                float s = SCALE ? dscale[r] : 1.f;
                long long o = r * M + n;
                float4 v = make_float4(c[i][0] * s, c[i][1] * s, c[i][2] * s, c[i][3] * s);
                *(float4*)&C[o] = v;
            }
        }
    }
}

// concat GEMM: C = [x | A2] @ B, K=192 (x stride 128, A2 stride 64), scale rows
__global__ __launch_bounds__(256)
void gemm64cat_k(const void* __restrict__ A, const int* __restrict__ fA,
                 const float* __restrict__ A2,
                 const void* __restrict__ B, const int* __restrict__ fB,
                 const float* __restrict__ dscale,
                 float* __restrict__ C, int NR, int M) {
    const int af = fA ? fA[0] : 1;
    const int bf = fB ? fB[0] : 1;
    __shared__ float As[16][68];
    __shared__ float Bs[16][68];
    const int t = threadIdx.x;
    const int tx = t & 15, ty = t >> 4;
    const long long m0 = (long long)blockIdx.x * 64;
    float c[4][4] = {};
    for (int k0 = 0; k0 < 192; k0 += 16) {
        {
            int row = t >> 2;
            int kk = (t & 3) * 4;
            long long r = m0 + row;
            float4 v = make_float4(0.f, 0.f, 0.f, 0.f);
            if (r < NR) {
                if (k0 < 128) {
                    long long base = r * 128 + k0 + kk;
                    if (af) v = *(const float4*)((const float*)A + base);
                    else {
                        v.x = ldf(A, 0, base); v.y = ldf(A, 0, base + 1);
                        v.z = ldf(A, 0, base + 2); v.w = ldf(A, 0, base + 3);
                    }
                } else {
                    v = *(const float4*)&A2[r * 64 + (k0 - 128) + kk];
                }
            }
            As[kk + 0][row] = v.x; As[kk + 1][row] = v.y;
            As[kk + 2][row] = v.z; As[kk + 3][row] = v.w;
        }
        {
            int krow = t >> 4;
            int nn = (t & 15) * 4;
            int k = k0 + krow;
            float4 v;
            long long base = (long long)k * M + nn;
            if (bf) v = *(const float4*)((const float*)B + base);
            else {
                v.x = ldf(B, 0, base); v.y = ldf(B, 0, base + 1);
                v.z = ldf(B, 0, base + 2); v.w = ldf(B, 0, base + 3);
            }
            *(float4*)&Bs[krow][nn] = v;
        }
        __syncthreads();
#pragma unroll
        for (int k = 0; k < 16; k++) {
            float4 a = *(const float4*)&As[k][ty * 4];
            float4 b = *(const float4*)&Bs[k][tx * 4];
            float av[4] = {a.x, a.y, a.z, a.w};
            float bv[4] = {b.x, b.y, b.z, b.w};
#pragma unroll
            for (int i = 0; i < 4; i++)
#pragma unroll
                for (int j = 0; j < 4; j++) c[i][j] = fmaf(av[i], bv[j], c[i][j]);
        }
        __syncthreads();
    }
    int n = tx * 4;
#pragma unroll
    for (int i = 0; i < 4; i++) {
        long long r = m0 + ty * 4 + i;
        if (r < NR) {
            float s = dscale[r];
            long long o = r * M + n;
            *(float4*)&C[o] = make_float4(c[i][0] * s, c[i][1] * s, c[i][2] * s, c[i][3] * s);
        }
    }
}

static inline dim3 g1d(long long n, int b) { return dim3((unsigned)((n + b - 1) / b)); }
static inline int imin(int a, int b) { return a < b ? a : b; }

extern "C" void kernel_launch(void* const* d_in, const int* in_sizes, int n_in,
                              void* d_out, int out_size, void* d_ws, size_t ws_size,
                              hipStream_t stream) {
    const int N  = in_sizes[0] / 128;   // 100000
    const int E  = in_sizes[1] / 2;     // 1600000
    const int P  = in_sizes[2] / 2;     // 800000
    const int HE = 20000;
    const int NC = in_sizes[9] / 64;    // 40
    const int nc4 = NC / 4;             // 10
    const int npw = 64 / nc4;           // 6 nodes per wave in final gather

    const void* x    = d_in[0];
    const int*  ew   = (const int*)d_in[1];
    const int*  hw   = (const int*)d_in[2];
    const void* W_h1 = d_in[3];
    const void* b_h1 = d_in[4];
    const void* W_h2 = d_in[5];
    const void* b_h2 = d_in[6];
    const void* W_c1 = d_in[7];
    const void* b_c1 = d_in[8];
    const void* W_c2 = d_in[9];
    const void* b_c2 = d_in[10];
    const void* W_lp = d_in[11];
    const void* b_lp = d_in[12];

    int shN = 0; while (((N - 1) >> shN) >= 256) shN++;   // 9
    int shH = 0; while (((HE - 1) >> shH) >= 256) shH++;  // 7

    // ---- workspace ----
    char* wp = (char*)d_ws;
    auto allocF = [&](size_t n) { float* p = (float*)wp; wp += n * 4; return p; };
    auto allocI = [&](size_t n) { int* p = (int*)wp; wp += n * 4; return p; };
    float* A0    = allocF((size_t)N * 64);
    float* A1    = allocF((size_t)N * 64);
    float* ef    = allocF((size_t)HE * 64);
    float* dis   = allocF(N);
    float* Dinv  = allocF(N);
    float* Binv  = allocF(HE);
    float* Wlp2  = allocF((size_t)64 * NC);
    float* bias2 = allocF(NC);
    int* ecnt  = allocI(N);
    int* pcntN = allocI(N);
    int* pcntH = allocI(HE);
    int* eoff  = allocI(N);
    int* poffN = allocI(N);
    int* poffH = allocI(HE);
    int* esrc  = allocI(E);
    int* pheL  = allocI(P);
    int* pniL  = allocI(P);
    int* gBkt  = allocI(768);
    int* bkOff = allocI(768);
    int* gcur  = allocI(768);
    int* FL    = allocI(16);
    unsigned* pbuf = (unsigned*)allocI((size_t)E + 2 * (size_t)P);

    dim3 b256(256), d1(1);

    // ---- dtype detection ----
    DPtrs dp;
    const void* farr[11] = {x, W_h1, b_h1, W_h2, b_h2, W_c1, b_c1, W_c2, b_c2, W_lp, b_lp};
    const int   fsz[11]  = {in_sizes[0], in_sizes[3], in_sizes[4], in_sizes[5], in_sizes[6],
                            in_sizes[7], in_sizes[8], in_sizes[9], in_sizes[10], in_sizes[11],
                            in_sizes[12]};
    for (int i = 0; i < 11; ++i) { dp.p[i] = farr[i]; dp.n[i] = fsz[i]; }
    dp.p[11] = ew; dp.n[11] = imin(E, 1024);
    dp.p[12] = hw; dp.n[12] = imin(P, 1024);
    detect_k<<<dim3(13), b256, 0, stream>>>(dp, FL);
    const int* fX   = FL + 0;
    const int* fWh1 = FL + 1,  *fbh1 = FL + 2;
    const int* fWh2 = FL + 3,  *fbh2 = FL + 4;
    const int* fWc1 = FL + 5,  *fbc1 = FL + 6;
    const int* fWc2 = FL + 7,  *fbc2 = FL + 8;
    const int* fWlp = FL + 9,  *fblp = FL + 10;

    // ---- CSR build ----
    hipMemsetAsync(gBkt, 0, 768 * 4, stream);
    bucket_count_k<<<dim3(512), b256, 0, stream>>>(ew, hw, FL, gBkt, E, P, N, HE, shN, shH);
    bucket_scan_k<<<d1, b256, 0, stream>>>(gBkt, bkOff, gcur, E, P);
    {
        long long T = (long long)E + P;
        int nChunks = (int)((T + PCHUNK - 1) / PCHUNK);
        bucket_place_k<<<dim3(nChunks), b256, 0, stream>>>(ew, hw, FL, gcur, pbuf,
                                                           E, P, N, HE, shN, shH);
    }
    build_k<<<dim3(768), b256, 0, stream>>>(pbuf, gBkt, bkOff,
                                            eoff, ecnt, esrc,
                                            poffN, pcntN, pheL,
                                            poffH, pcntH, pniL,
                                            E, P, N, HE, shN, shH);

    // ---- norms + fused tail weights ----
    norms_k<<<g1d(2 * N + HE, 256), b256, 0, stream>>>(ecnt, pcntN, pcntH, dis, Dinv, Binv, N, HE);
    wlp2_k<<<d1, b256, 0, stream>>>(W_c2, fWc2, W_lp, fWlp, b_c2, fbc2, b_lp, fblp, Wlp2, bias2, NC);

    const dim3 gemmGrid((N + 63) / 64);
    const dim3 gatN16(g1d((long long)N * 16, 256));    // 16 threads per node
    const dim3 gatH16(g1d((long long)HE * 16, 256));   // 16 threads per hyperedge
    const dim3 gatNC(g1d((long long)((N + npw - 1) / npw) * 64, 256));

    // ---- hyperconv 1 ----
    gemm64_k<false><<<gemmGrid, b256, 0, stream>>>(x, fX, W_h1, fWh1, nullptr, A0, N, 128, 64);
    gat_n2e4_k<<<gatH16, b256, 0, stream>>>((const float4*)A0, poffH, pcntH, pniL, Binv, (float4*)ef, HE);
    gat_e2n4_k<true><<<gatN16, b256, 0, stream>>>((const float4*)ef, poffN, pcntN, pheL, Dinv, b_h1, fbh1, (float4*)A1, N);

    // ---- hyperconv 2 ----
    gemm64_k<false><<<gemmGrid, b256, 0, stream>>>(A1, nullptr, W_h2, fWh2, nullptr, A0, N, 64, 64);
    gat_n2e4_k<<<gatH16, b256, 0, stream>>>((const float4*)A0, poffH, pcntH, pniL, Binv, (float4*)ef, HE);
    gat_e2n4_k<false><<<gatN16, b256, 0, stream>>>((const float4*)ef, poffN, pcntN, pheL, Dinv, b_h2, fbh2, (float4*)A1, N);
    // A1 = x_hyper

    // ---- gcn 1: y = ([x|x_hyper] @ W_c1) * dis, then gather ----
    gemm64cat_k<<<gemmGrid, b256, 0, stream>>>(x, fX, A1, W_c1, fWc1, dis, A0, N, 64);
    gcn_gat4_k<true><<<gatN16, b256, 0, stream>>>((const float4*)A0, eoff, ecnt, esrc, dis, b_c1, fbc1, (float4*)A1, N);

    // ---- gcn 2 + final linear fused: y = (A1 @ Wlp2) * dis, gather -> out ---
    gemm64_k<true><<<gemmGrid, b256, 0, stream>>>(A1, nullptr, Wlp2, nullptr, dis, A0, N, 64, NC);
    gcn_gatM4_k<<<gatNC, b256, 0, stream>>>((const float4*)A0, eoff, ecnt, esrc, dis, bias2, (float4*)d_out, N, nc4, npw);
}

// Round 8
// 541.946 us; speedup vs baseline: 2.1296x; 1.2313x over previous
//
#include <hip/hip_runtime.h>
#include <hip/hip_bf16.h>

// ---------------------------------------------------------------------------
// LPGCNHyperConvAblation, round 8: bf16-packed gather operands (fused into
// GEMM epilogues), 4-wide unrolled gathers. fp32 accumulation everywhere.
// ---------------------------------------------------------------------------

__device__ __forceinline__ float ldf(const void* p, int f32, long long i) {
    if (f32) return ((const float*)p)[i];
    unsigned v = ((unsigned)((const unsigned short*)p)[i]) << 16;
    return __uint_as_float(v);
}

__device__ __forceinline__ int ldi(const int* __restrict__ w, int i64, long long i, int lim) {
    int v = i64 ? w[2 * i] : w[i];
    return ((unsigned)v < (unsigned)lim) ? v : 0;
}

__device__ __forceinline__ float b2f(unsigned short u) {
    return __uint_as_float(((unsigned)u) << 16);
}
__device__ __forceinline__ unsigned short f2b(float f) {
    __hip_bfloat16 h = __float2bfloat16(f);
    return *reinterpret_cast<unsigned short*>(&h);
}
__device__ __forceinline__ float4 b2f4(ushort4 u) {
    return make_float4(b2f(u.x), b2f(u.y), b2f(u.z), b2f(u.w));
}
__device__ __forceinline__ ushort4 f2b4(float4 v) {
    ushort4 u; u.x = f2b(v.x); u.y = f2b(v.y); u.z = f2b(v.z); u.w = f2b(v.w);
    return u;
}

// --- fused dtype detection ---------------------------------------------------
struct DPtrs { const void* p[13]; int n[13]; };

__global__ void detect_k(DPtrs dp, int* __restrict__ flags) {
    int b = blockIdx.x;
    __shared__ int cnt;
    if (threadIdx.x == 0) cnt = 0;
    __syncthreads();
    int c = 0;
    if (b < 11) {
        const unsigned short* u = (const unsigned short*)dp.p[b];
        int np = dp.n[b]; if (np > 2048) np = 2048;
        for (int i = threadIdx.x; i < np; i += blockDim.x) {
            unsigned e = (u[i] >> 7) & 0xFFu;
            if (e != 0u && (e < 90u || e > 160u)) c++;
        }
        atomicAdd(&cnt, c);
        __syncthreads();
        if (threadIdx.x == 0) flags[b] = (cnt * 8 > np) ? 1 : 0;
    } else {
        const int* w = (const int*)dp.p[b];
        int np = dp.n[b]; if (np > 1024) np = 1024;
        for (int i = threadIdx.x; i < np; i += blockDim.x)
            if (w[2 * i + 1] != 0) c++;
        atomicAdd(&cnt, c);
        __syncthreads();
        if (threadIdx.x == 0) flags[b] = (cnt == 0) ? 1 : 0;
    }
}

// --- CSR build (atomic-free pipeline, unchanged from round 6) ----------------
struct Item { int b1; unsigned p1; int b2; unsigned p2; };

__device__ __forceinline__ Item decode(const int* __restrict__ ew, const int* __restrict__ hw,
                                       const int* __restrict__ FL, long long i,
                                       int E, int P, int N, int HE, int shN, int shH) {
    Item it; it.b2 = -1; it.p2 = 0;
    if (i < E) {
        int g = FL[11];
        int key = ldi(ew, g, (long long)E + i, N);
        int val = ldi(ew, g, i, N);
        it.b1 = key >> shN;
        it.p1 = ((unsigned)(key & ((1 << shN) - 1)) << 20) | (unsigned)val;
    } else {
        long long j = i - E;
        int g = FL[12];
        int nd = ldi(hw, g, j, N);
        int he = ldi(hw, g, (long long)P + j, HE);
        it.b1 = 256 + (nd >> shN);
        it.p1 = ((unsigned)(nd & ((1 << shN) - 1)) << 20) | (unsigned)he;
        it.b2 = 512 + (he >> shH);
        it.p2 = ((unsigned)(he & ((1 << shH) - 1)) << 20) | (unsigned)nd;
    }
    return it;
}

__global__ void bucket_count_k(const int* __restrict__ ew, const int* __restrict__ hw,
                               const int* __restrict__ FL, int* __restrict__ gcnt,
                               int E, int P, int N, int HE, int shN, int shH) {
    __shared__ int hist[768];
    int t = threadIdx.x;
    for (int b = t; b < 768; b += 256) hist[b] = 0;
    __syncthreads();
    long long T = (long long)E + P;
    long long stride = (long long)gridDim.x * 256;
    for (long long i = (long long)blockIdx.x * 256 + t; i < T; i += stride) {
        Item it = decode(ew, hw, FL, i, E, P, N, HE, shN, shH);
        atomicAdd(&hist[it.b1], 1);
        if (it.b2 >= 0) atomicAdd(&hist[it.b2], 1);
    }
    __syncthreads();
    for (int b = t; b < 768; b += 256) {
        int h = hist[b];
        if (h) atomicAdd(&gcnt[b], h);
    }
}

__global__ void bucket_scan_k(const int* __restrict__ gcnt, int* __restrict__ bkOff,
                              int* __restrict__ gcur, int E, int P) {
    __shared__ int sh[256];
    int t = threadIdx.x;
    long long rbase[3] = {0, (long long)E, (long long)E + P};
    for (int c = 0; c < 3; c++) {
        int v = gcnt[c * 256 + t];
        sh[t] = v;
        __syncthreads();
        for (int o = 1; o < 256; o <<= 1) {
            int y = (t >= o) ? sh[t - o] : 0;
            __syncthreads();
            sh[t] += y;
            __syncthreads();
        }
        int excl = sh[t] - v;
        bkOff[c * 256 + t] = excl;
        gcur[c * 256 + t] = (int)(rbase[c] + excl);
        __syncthreads();
    }
}

#define PCHUNK 8192

__global__ void bucket_place_k(const int* __restrict__ ew, const int* __restrict__ hw,
                               const int* __restrict__ FL, int* __restrict__ gcur,
                               unsigned* __restrict__ pbuf,
                               int E, int P, int N, int HE, int shN, int shH) {
    __shared__ int hist[768];
    __shared__ int cur[768];
    long long T = (long long)E + P;
    long long start = (long long)blockIdx.x * PCHUNK;
    long long end = start + PCHUNK; if (end > T) end = T;
    int t = threadIdx.x;
    for (int b = t; b < 768; b += 256) hist[b] = 0;
    __syncthreads();
    for (long long i = start + t; i < end; i += 256) {
        Item it = decode(ew, hw, FL, i, E, P, N, HE, shN, shH);
        atomicAdd(&hist[it.b1], 1);
        if (it.b2 >= 0) atomicAdd(&hist[it.b2], 1);
    }
    __syncthreads();
    for (int b = t; b < 768; b += 256) {
        int h = hist[b];
        cur[b] = h ? atomicAdd(&gcur[b], h) : 0;
    }
    __syncthreads();
    for (long long i = start + t; i < end; i += 256) {
        Item it = decode(ew, hw, FL, i, E, P, N, HE, shN, shH);
        int s1 = atomicAdd(&cur[it.b1], 1);
        pbuf[s1] = it.p1;
        if (it.b2 >= 0) {
            int s2 = atomicAdd(&cur[it.b2], 1);
            pbuf[s2] = it.p2;
        }
    }
}

__global__ void build_k(const unsigned* __restrict__ pbuf,
                        const int* __restrict__ gcnt, const int* __restrict__ bkOff,
                        int* __restrict__ eoff, int* __restrict__ ecnt, int* __restrict__ esrc,
                        int* __restrict__ poffN, int* __restrict__ pcntN, int* __restrict__ pheL,
                        int* __restrict__ poffH, int* __restrict__ pcntH, int* __restrict__ pniL,
                        int E, int P, int N, int HE, int shN, int shH) {
    __shared__ int hist[512];
    __shared__ int offs[512];
    __shared__ int s2[256];
    int b = blockIdx.x, t = threadIdx.x;
    int csr = b >> 8, lb = b & 255;
    int sh    = (csr == 2) ? shH : shN;
    int nkeys = (csr == 2) ? HE : N;
    int span = 1 << sh;
    int keyBase = lb << sh;
    if (keyBase >= nkeys) return;
    int keyEnd = keyBase + span; if (keyEnd > nkeys) keyEnd = nkeys;
    int cnt = gcnt[b];
    long long rbase = (csr == 0) ? 0 : ((csr == 1) ? (long long)E : (long long)E + P);
    long long pstart = rbase + bkOff[b];
    int lstBase = bkOff[b];
    int* off  = (csr == 0) ? eoff : ((csr == 1) ? poffN : poffH);
    int* cntA = (csr == 0) ? ecnt : ((csr == 1) ? pcntN : pcntH);
    int* lst  = (csr == 0) ? esrc : ((csr == 1) ? pheL : pniL);

    for (int k = t; k < 512; k += 256) hist[k] = 0;
    __syncthreads();
    for (int i = t; i < cnt; i += 256)
        atomicAdd(&hist[pbuf[pstart + i] >> 20], 1);
    __syncthreads();
    int a0 = hist[2 * t], a1 = hist[2 * t + 1];
    s2[t] = a0 + a1;
    __syncthreads();
    for (int o = 1; o < 256; o <<= 1) {
        int y = (t >= o) ? s2[t - o] : 0;
        __syncthreads();
        s2[t] += y;
        __syncthreads();
    }
    int excl = s2[t] - (a0 + a1);
    offs[2 * t] = excl;
    offs[2 * t + 1] = excl + a0;
    __syncthreads();
    for (int k = keyBase + t; k < keyEnd; k += 256) {
        off[k]  = lstBase + offs[k - keyBase];
        cntA[k] = hist[k - keyBase];
    }
    __syncthreads();
    for (int i = t; i < cnt; i += 256) {
        unsigned u = pbuf[pstart + i];
        int lk = u >> 20;
        int slot = atomicAdd(&offs[lk], 1);
        lst[lstBase + slot] = (int)(u & 0xFFFFFu);
    }
}

// --- fused norm factors ------------------------------------------------------
__global__ void norms_k(const int* __restrict__ ecnt, const int* __restrict__ pcntN,
                        const int* __restrict__ pcntH, float* __restrict__ dis,
                        float* __restrict__ Dinv, float* __restrict__ Binv, int N, int HE) {
    int i = blockIdx.x * blockDim.x + threadIdx.x;
    if (i < N) dis[i] = rsqrtf((float)(ecnt[i] + 1));
    else if (i < 2 * N) { int c = pcntN[i - N]; Dinv[i - N] = c ? (1.f / (float)c) : 0.f; }
    else if (i < 2 * N + HE) { int c = pcntH[i - 2 * N]; Binv[i - 2 * N] = c ? (1.f / (float)c) : 0.f; }
}

// --- Wlp2 = W_c2 @ W_lp, bias2 = b_c2 @ W_lp + b_lp --------------------------
__global__ void wlp2_k(const void* Wc2, const int* fWc2, const void* Wlp, const int* fWlp,
                       const void* bc2, const int* fbc2, const void* blp, const int* fblp,
                       float* __restrict__ Wlp2, float* __restrict__ bias2, int NC) {
    int t = threadIdx.x;
    for (int e = t; e < 64 * NC; e += blockDim.x) {
        int r = e / NC, c = e % NC;
        float s = 0.f;
        for (int k = 0; k < NC; k++)
            s += ldf(Wc2, fWc2[0], r * NC + k) * ldf(Wlp, fWlp[0], k * NC + c);
        Wlp2[e] = s;
    }
    for (int c = t; c < NC; c += blockDim.x) {
        float s = ldf(blp, fblp[0], c);
        for (int k = 0; k < NC; k++)
            s += ldf(bc2, fbc2[0], k) * ldf(Wlp, fWlp[0], k * NC + c);
        bias2[c] = s;
    }
}

// --- bf16 gathers: 4 rows/wave, 16 lanes x ushort4 (D=64) --------------------
// node -> hyperedge: ef[e] = Binv[e] * sum xw[n]   (bf16 in, bf16 out)
__global__ void gat_n2e_k(const ushort4* __restrict__ xw, const int* __restrict__ off,
                          const int* __restrict__ cnt, const int* __restrict__ lst,
                          const float* __restrict__ Binv, ushort4* __restrict__ ef, int HE) {
    int idx = blockIdx.x * blockDim.x + threadIdx.x;
    int e = idx >> 4, l = idx & 15;
    if (e >= HE) return;
    int o = off[e], c = cnt[e];
    float4 a = make_float4(0.f, 0.f, 0.f, 0.f);
    int j = 0;
    for (; j + 4 <= c; j += 4) {
        int s0 = lst[o + j], s1 = lst[o + j + 1], s2 = lst[o + j + 2], s3 = lst[o + j + 3];
        float4 v0 = b2f4(xw[((long long)s0 << 4) + l]);
        float4 v1 = b2f4(xw[((long long)s1 << 4) + l]);
        float4 v2 = b2f4(xw[((long long)s2 << 4) + l]);
        float4 v3 = b2f4(xw[((long long)s3 << 4) + l]);
        a.x += (v0.x + v1.x) + (v2.x + v3.x);
        a.y += (v0.y + v1.y) + (v2.y + v3.y);
        a.z += (v0.z + v1.z) + (v2.z + v3.z);
        a.w += (v0.w + v1.w) + (v2.w + v3.w);
    }
    for (; j < c; j++) {
        float4 v = b2f4(xw[((long long)lst[o + j] << 4) + l]);
        a.x += v.x; a.y += v.y; a.z += v.z; a.w += v.w;
    }
    float bi = Binv[e];
    a.x *= bi; a.y *= bi; a.z *= bi; a.w *= bi;
    ef[((long long)e << 4) + l] = f2b4(a);
}

// hyperedge -> node: out[n] = Dinv[n]*sum ef[e] + bias (+relu)  (bf16 in, f32 out)
template <bool RELU>
__global__ void gat_e2n_k(const ushort4* __restrict__ ef, const int* __restrict__ off,
                          const int* __restrict__ cnt, const int* __restrict__ lst,
                          const float* __restrict__ Dinv, const void* __restrict__ bias,
                          const int* __restrict__ fb, float4* __restrict__ out4, int N) {
    int idx = blockIdx.x * blockDim.x + threadIdx.x;
    int w = idx >> 4, l = idx & 15;
    if (w >= N) return;
    int o = off[w], c = cnt[w];
    float4 a = make_float4(0.f, 0.f, 0.f, 0.f);
    int j = 0;
    for (; j + 4 <= c; j += 4) {
        int s0 = lst[o + j], s1 = lst[o + j + 1], s2 = lst[o + j + 2], s3 = lst[o + j + 3];
        float4 v0 = b2f4(ef[((long long)s0 << 4) + l]);
        float4 v1 = b2f4(ef[((long long)s1 << 4) + l]);
        float4 v2 = b2f4(ef[((long long)s2 << 4) + l]);
        float4 v3 = b2f4(ef[((long long)s3 << 4) + l]);
        a.x += (v0.x + v1.x) + (v2.x + v3.x);
        a.y += (v0.y + v1.y) + (v2.y + v3.y);
        a.z += (v0.z + v1.z) + (v2.z + v3.z);
        a.w += (v0.w + v1.w) + (v2.w + v3.w);
    }
    for (; j < c; j++) {
        float4 v = b2f4(ef[((long long)lst[o + j] << 4) + l]);
        a.x += v.x; a.y += v.y; a.z += v.z; a.w += v.w;
    }
    float di = Dinv[w];
    int fbv = fb[0];
    float4 b = make_float4(ldf(bias, fbv, 4 * l), ldf(bias, fbv, 4 * l + 1),
                           ldf(bias, fbv, 4 * l + 2), ldf(bias, fbv, 4 * l + 3));
    a.x = a.x * di + b.x; a.y = a.y * di + b.y;
    a.z = a.z * di + b.z; a.w = a.w * di + b.w;
    if (RELU) {
        a.x = fmaxf(a.x, 0.f); a.y = fmaxf(a.y, 0.f);
        a.z = fmaxf(a.z, 0.f); a.w = fmaxf(a.w, 0.f);
    }
    out4[((long long)w << 4) + l] = a;
}

// GCN aggregation on pre-scaled bf16 y: out[d] = dis[d]*(y[d]+sum y[s]) + b (+relu)
template <bool RELU>
__global__ void gcn_gat_k(const ushort4* __restrict__ y, const int* __restrict__ off,
                          const int* __restrict__ cnt, const int* __restrict__ lst,
                          const float* __restrict__ dis, const void* __restrict__ bias,
                          const int* __restrict__ fb, float4* __restrict__ out4, int N) {
    int idx = blockIdx.x * blockDim.x + threadIdx.x;
    int w = idx >> 4, l = idx & 15;
    if (w >= N) return;
    int o = off[w], c = cnt[w];
    float4 a = b2f4(y[((long long)w << 4) + l]);   // self term (= xw[d]*dis[d])
    int j = 0;
    for (; j + 4 <= c; j += 4) {
        int s0 = lst[o + j], s1 = lst[o + j + 1], s2 = lst[o + j + 2], s3 = lst[o + j + 3];
        float4 v0 = b2f4(y[((long long)s0 << 4) + l]);
        float4 v1 = b2f4(y[((long long)s1 << 4) + l]);
        float4 v2 = b2f4(y[((long long)s2 << 4) + l]);
        float4 v3 = b2f4(y[((long long)s3 << 4) + l]);
        a.x += (v0.x + v1.x) + (v2.x + v3.x);
        a.y += (v0.y + v1.y) + (v2.y + v3.y);
        a.z += (v0.z + v1.z) + (v2.z + v3.z);
        a.w += (v0.w + v1.w) + (v2.w + v3.w);
    }
    for (; j < c; j++) {
        float4 v = b2f4(y[((long long)lst[o + j] << 4) + l]);
        a.x += v.x; a.y += v.y; a.z += v.z; a.w += v.w;
    }
    float dd = dis[w];
    int fbv = fb[0];
    float4 b = make_float4(ldf(bias, fbv, 4 * l), ldf(bias, fbv, 4 * l + 1),
                           ldf(bias, fbv, 4 * l + 2), ldf(bias, fbv, 4 * l + 3));
    a.x = a.x * dd + b.x; a.y = a.y * dd + b.y;
    a.z = a.z * dd + b.z; a.w = a.w * dd + b.w;
    if (RELU) {
        a.x = fmaxf(a.x, 0.f); a.y = fmaxf(a.y, 0.f);
        a.z = fmaxf(a.z, 0.f); a.w = fmaxf(a.w, 0.f);
    }
    out4[((long long)w << 4) + l] = a;
}

// final GCN aggregation over bf16 y2 (M=NC, nc4 ushort4 lanes), writes d_out f32
__global__ void gcn_gatM_k(const ushort4* __restrict__ y2, const int* __restrict__ off,
                           const int* __restrict__ cnt, const int* __restrict__ lst,
                           const float* __restrict__ dis, const float* __restrict__ bias2,
                           float4* __restrict__ out4, int N, int nc4, int npw) {
    int idx = blockIdx.x * blockDim.x + threadIdx.x;
    int wave = idx >> 6, l64 = idx & 63;
    int grp = l64 / 10, li = l64 - grp * 10;
    if (nc4 != 10) { grp = l64 / nc4; li = l64 - grp * nc4; }
    int w = wave * npw + grp;
    if (grp >= npw || w >= N) return;
    int o = off[w], c = cnt[w];
    float4 a = b2f4(y2[(long long)w * nc4 + li]);  // self term
    int j = 0;
    for (; j + 4 <= c; j += 4) {
        int s0 = lst[o + j], s1 = lst[o + j + 1], s2 = lst[o + j + 2], s3 = lst[o + j + 3];
        float4 v0 = b2f4(y2[(long long)s0 * nc4 + li]);
        float4 v1 = b2f4(y2[(long long)s1 * nc4 + li]);
        float4 v2 = b2f4(y2[(long long)s2 * nc4 + li]);
        float4 v3 = b2f4(y2[(long long)s3 * nc4 + li]);
        a.x += (v0.x + v1.x) + (v2.x + v3.x);
        a.y += (v0.y + v1.y) + (v2.y + v3.y);
        a.z += (v0.z + v1.z) + (v2.z + v3.z);
        a.w += (v0.w + v1.w) + (v2.w + v3.w);
    }
    for (; j < c; j++) {
        float4 v = b2f4(y2[(long long)lst[o + j] * nc4 + li]);
        a.x += v.x; a.y += v.y; a.z += v.z; a.w += v.w;
    }
    float dd = dis[w];
    float4 b = *(const float4*)&bias2[4 * li];
    a.x = a.x * dd + b.x; a.y = a.y * dd + b.y;
    a.z = a.z * dd + b.z; a.w = a.w * dd + b.w;
    out4[(long long)w * nc4 + li] = a;
}

// --- GEMM: 64x64 tile, 4x4 micro-tile, float4; optional row-scale, bf16 out --
template <bool SCALE, bool BF16OUT>
__global__ __launch_bounds__(256)
void gemm64_k(const void* __restrict__ A, const int* __restrict__ fA,
              const void* __restrict__ B, const int* __restrict__ fB,
              const float* __restrict__ dscale,
              void* __restrict__ C, int NR, int K, int M) {
    const int af = fA ? fA[0] : 1;
    const int bf = fB ? fB[0] : 1;
    __shared__ float As[16][68];
    __shared__ float Bs[16][68];
    const int t = threadIdx.x;
    const int tx = t & 15, ty = t >> 4;
    const long long m0 = (long long)blockIdx.x * 64;
    float c[4][4] = {};
    for (int k0 = 0; k0 < K; k0 += 16) {
        {
            int row = t >> 2;
            int kk = (t & 3) * 4;
            long long r = m0 + row;
            float4 v = make_float4(0.f, 0.f, 0.f, 0.f);
            if (r < NR) {
                long long base = r * K + k0 + kk;
                if (af) v = *(const float4*)((const float*)A + base);
                else {
                    v.x = ldf(A, 0, base); v.y = ldf(A, 0, base + 1);
                    v.z = ldf(A, 0, base + 2); v.w = ldf(A, 0, base + 3);
                }
            }
            As[kk + 0][row] = v.x; As[kk + 1][row] = v.y;
            As[kk + 2][row] = v.z; As[kk + 3][row] = v.w;
        }
        {
            int krow = t >> 4;
            int nn = (t & 15) * 4;
            int k = k0 + krow;
            float4 v = make_float4(0.f, 0.f, 0.f, 0.f);
            if (nn < M) {
                long long base = (long long)k * M + nn;
                if (bf) v = *(const float4*)((const float*)B + base);
                else {
                    v.x = ldf(B, 0, base); v.y = ldf(B, 0, base + 1);
                    v.z = ldf(B, 0, base + 2); v.w = ldf(B, 0, base + 3);
                }
            }
            *(float4*)&Bs[krow][nn] = v;
        }
        __syncthreads();
#pragma unroll
        for (int k = 0; k < 16; k++) {
            float4 a = *(const float4*)&As[k][ty * 4];
            float4 b = *(const float4*)&Bs[k][tx * 4];
            float av[4] = {a.x, a.y, a.z, a.w};
            float bv[4] = {b.x, b.y, b.z, b.w};
#pragma unroll
            for (int i = 0; i < 4; i++)
#pragma unroll
                for (int j = 0; j < 4; j++) c[i][j] = fmaf(av[i], bv[j], c[i][j]);
        }
        __syncthreads();
    }
    int n = tx * 4;
    if (n < M) {
#pragma unroll
        for (int i = 0; i < 4; i++) {
            long long r = m0 + ty * 4 + i;
            if (r < NR) {
                float s = SCALE ? dscale[r] : 1.f;
                long long o = r * M + n;
                float4 v = make_float4(c[i][0] * s, c[i][1] * s, c[i][2] * s, c[i][3] * s);
                if constexpr (BF16OUT) *(ushort4*)&((unsigned short*)C)[o] = f2b4(v);
                else                   *(float4*)&((float*)C)[o] = v;
            }
        }
    }
}

// concat GEMM: C = [x | A2] @ B, K=192, row-scaled, bf16 out
__global__ __launch_bounds__(256)
void gemm64cat_k(const void* __restrict__ A, const int* __restrict__ fA,
                 const float* __restrict__ A2,
                 const void* __restrict__ B, const int* __restrict__ fB,
                 const float* __restrict__ dscale,
                 unsigned short* __restrict__ C, int NR, int M) {
    const int af = fA ? fA[0] : 1;
    const int bf = fB ? fB[0] : 1;
    __shared__ float As[16][68];
    __shared__ float Bs[16][68];
    const int t = threadIdx.x;
    const int tx = t & 15, ty = t >> 4;
    const long long m0 = (long long)blockIdx.x * 64;
    float c[4][4] = {};
    for (int k0 = 0; k0 < 192; k0 += 16) {
        {
            int row = t >> 2;
            int kk = (t & 3) * 4;
            long long r = m0 + row;
            float4 v = make_float4(0.f, 0.f, 0.f, 0.f);
            if (r < NR) {
                if (k0 < 128) {
                    long long base = r * 128 + k0 + kk;
                    if (af) v = *(const float4*)((const float*)A + base);
                    else {
                        v.x = ldf(A, 0, base); v.y = ldf(A, 0, base + 1);
                        v.z = ldf(A, 0, base + 2); v.w = ldf(A, 0, base + 3);
                    }
                } else {
                    v = *(const float4*)&A2[r * 64 + (k0 - 128) + kk];
                }
            }
            As[kk + 0][row] = v.x; As[kk + 1][row] = v.y;
            As[kk + 2][row] = v.z; As[kk + 3][row] = v.w;
        }
        {
            int krow = t >> 4;
            int nn = (t & 15) * 4;
            int k = k0 + krow;
            float4 v;
            long long base = (long long)k * M + nn;
            if (bf) v = *(const float4*)((const float*)B + base);
            else {
                v.x = ldf(B, 0, base); v.y = ldf(B, 0, base + 1);
                v.z = ldf(B, 0, base + 2); v.w = ldf(B, 0, base + 3);
            }
            *(float4*)&Bs[krow][nn] = v;
        }
        __syncthreads();
#pragma unroll
        for (int k = 0; k < 16; k++) {
            float4 a = *(const float4*)&As[k][ty * 4];
            float4 b = *(const float4*)&Bs[k][tx * 4];
            float av[4] = {a.x, a.y, a.z, a.w};
            float bv[4] = {b.x, b.y, b.z, b.w};
#pragma unroll
            for (int i = 0; i < 4; i++)
#pragma unroll
                for (int j = 0; j < 4; j++) c[i][j] = fmaf(av[i], bv[j], c[i][j]);
        }
        __syncthreads();
    }
    int n = tx * 4;
#pragma unroll
    for (int i = 0; i < 4; i++) {
        long long r = m0 + ty * 4 + i;
        if (r < NR) {
            float s = dscale[r];
            long long o = r * M + n;
            *(ushort4*)&C[o] = f2b4(make_float4(c[i][0] * s, c[i][1] * s,
                                                c[i][2] * s, c[i][3] * s));
        }
    }
}

static inline dim3 g1d(long long n, int b) { return dim3((unsigned)((n + b - 1) / b)); }
static inline int imin(int a, int b) { return a < b ? a : b; }

extern "C" void kernel_launch(void* const* d_in, const int* in_sizes, int n_in,
                              void* d_out, int out_size, void* d_ws, size_t ws_size,
                              hipStream_t stream) {
    const int N  = in_sizes[0] / 128;   // 100000
    const int E  = in_sizes[1] / 2;     // 1600000
    const int P  = in_sizes[2] / 2;     // 800000
    const int HE = 20000;
    const int NC = in_sizes[9] / 64;    // 40
    const int nc4 = NC / 4;             // 10
    const int npw = 64 / nc4;           // 6

    const void* x    = d_in[0];
    const int*  ew   = (const int*)d_in[1];
    const int*  hw   = (const int*)d_in[2];
    const void* W_h1 = d_in[3];
    const void* b_h1 = d_in[4];
    const void* W_h2 = d_in[5];
    const void* b_h2 = d_in[6];
    const void* W_c1 = d_in[7];
    const void* b_c1 = d_in[8];
    const void* W_c2 = d_in[9];
    const void* b_c2 = d_in[10];
    const void* W_lp = d_in[11];
    const void* b_lp = d_in[12];

    int shN = 0; while (((N - 1) >> shN) >= 256) shN++;   // 9
    int shH = 0; while (((HE - 1) >> shH) >= 256) shH++;  // 7

    // ---- workspace ----
    char* wp = (char*)d_ws;
    auto allocF = [&](size_t n) { float* p = (float*)wp; wp += n * 4; return p; };
    auto allocI = [&](size_t n) { int* p = (int*)wp; wp += n * 4; return p; };
    float* A0    = allocF((size_t)N * 64);            // fp32 stage buffer
    unsigned short* ub  = (unsigned short*)allocF((size_t)N * 32);   // bf16 N*64
    unsigned short* efb = (unsigned short*)allocF((size_t)HE * 32);  // bf16 HE*64
    float* dis   = allocF(N);
    float* Dinv  = allocF(N);
    float* Binv  = allocF(HE);
    float* Wlp2  = allocF((size_t)64 * NC);
    float* bias2 = allocF(NC);
    int* ecnt  = allocI(N);
    int* pcntN = allocI(N);
    int* pcntH = allocI(HE);
    int* eoff  = allocI(N);
    int* poffN = allocI(N);
    int* poffH = allocI(HE);
    int* esrc  = allocI(E);
    int* pheL  = allocI(P);
    int* pniL  = allocI(P);
    int* gBkt  = allocI(768);
    int* bkOff = allocI(768);
    int* gcur  = allocI(768);
    int* FL    = allocI(16);
    unsigned* pbuf = (unsigned*)allocI((size_t)E + 2 * (size_t)P);

    dim3 b256(256), d1(1);

    // ---- dtype detection ----
    DPtrs dp;
    const void* farr[11] = {x, W_h1, b_h1, W_h2, b_h2, W_c1, b_c1, W_c2, b_c2, W_lp, b_lp};
    const int   fsz[11]  = {in_sizes[0], in_sizes[3], in_sizes[4], in_sizes[5], in_sizes[6],
                            in_sizes[7], in_sizes[8], in_sizes[9], in_sizes[10], in_sizes[11],
                            in_sizes[12]};
    for (int i = 0; i < 11; ++i) { dp.p[i] = farr[i]; dp.n[i] = fsz[i]; }
    dp.p[11] = ew; dp.n[11] = imin(E, 1024);
    dp.p[12] = hw; dp.n[12] = imin(P, 1024);
    detect_k<<<dim3(13), b256, 0, stream>>>(dp, FL);
    const int* fX   = FL + 0;
    const int* fWh1 = FL + 1,  *fbh1 = FL + 2;
    const int* fWh2 = FL + 3,  *fbh2 = FL + 4;
    const int* fWc1 = FL + 5,  *fbc1 = FL + 6;
    const int* fWc2 = FL + 7,  *fbc2 = FL + 8;
    const int* fWlp = FL + 9,  *fblp = FL + 10;

    // ---- CSR build ----
    hipMemsetAsync(gBkt, 0, 768 * 4, stream);
    bucket_count_k<<<dim3(512), b256, 0, stream>>>(ew, hw, FL, gBkt, E, P, N, HE, shN, shH);
    bucket_scan_k<<<d1, b256, 0, stream>>>(gBkt, bkOff, gcur, E, P);
    {
        long long T = (long long)E + P;
        int nChunks = (int)((T + PCHUNK - 1) / PCHUNK);
        bucket_place_k<<<dim3(nChunks), b256, 0, stream>>>(ew, hw, FL, gcur, pbuf,
                                                           E, P, N, HE, shN, shH);
    }
    build_k<<<dim3(768), b256, 0, stream>>>(pbuf, gBkt, bkOff,
                                            eoff, ecnt, esrc,
                                            poffN, pcntN, pheL,
                                            poffH, pcntH, pniL,
                                            E, P, N, HE, shN, shH);

    // ---- norms + fused tail weights ----
    norms_k<<<g1d(2 * N + HE, 256), b256, 0, stream>>>(ecnt, pcntN, pcntH, dis, Dinv, Binv, N, HE);
    wlp2_k<<<d1, b256, 0, stream>>>(W_c2, fWc2, W_lp, fWlp, b_c2, fbc2, b_lp, fblp, Wlp2, bias2, NC);

    const dim3 gemmGrid((N + 63) / 64);
    const dim3 gatN16(g1d((long long)N * 16, 256));
    const dim3 gatH16(g1d((long long)HE * 16, 256));
    const dim3 gatNC(g1d((long long)((N + npw - 1) / npw) * 64, 256));

    // ---- hyperconv 1 ----
    gemm64_k<false, true><<<gemmGrid, b256, 0, stream>>>(x, fX, W_h1, fWh1, nullptr, ub, N, 128, 64);
    gat_n2e_k<<<gatH16, b256, 0, stream>>>((const ushort4*)ub, poffH, pcntH, pniL, Binv, (ushort4*)efb, HE);
    gat_e2n_k<true><<<gatN16, b256, 0, stream>>>((const ushort4*)efb, poffN, pcntN, pheL, Dinv, b_h1, fbh1, (float4*)A0, N);

    // ---- hyperconv 2 ----
    gemm64_k<false, true><<<gemmGrid, b256, 0, stream>>>(A0, nullptr, W_h2, fWh2, nullptr, ub, N, 64, 64);
    gat_n2e_k<<<gatH16, b256, 0, stream>>>((const ushort4*)ub, poffH, pcntH, pniL, Binv, (ushort4*)efb, HE);
    gat_e2n_k<false><<<gatN16, b256, 0, stream>>>((const ushort4*)efb, poffN, pcntN, pheL, Dinv, b_h2, fbh2, (float4*)A0, N);
    // A0 = x_hyper (fp32)

    // ---- gcn 1: y = ([x|x_hyper] @ W_c1) * dis  (bf16), then gather ----
    gemm64cat_k<<<gemmGrid, b256, 0, stream>>>(x, fX, A0, W_c1, fWc1, dis, ub, N, 64);
    gcn_gat_k<true><<<gatN16, b256, 0, stream>>>((const ushort4*)ub, eoff, ecnt, esrc, dis, b_c1, fbc1, (float4*)A0, N);

    // ---- gcn 2 + final linear fused: y2 = (A0 @ Wlp2) * dis (bf16), gather ----
    gemm64_k<true, true><<<gemmGrid, b256, 0, stream>>>(A0, nullptr, Wlp2, nullptr, dis, ub, N, 64, NC);
    gcn_gatM_k<<<gatNC, b256, 0, stream>>>((const ushort4*)ub, eoff, ecnt, esrc, dis, bias2, (float4*)d_out, N, nc4, npw);
}

// Round 9
// 497.114 us; speedup vs baseline: 2.3216x; 1.0902x over previous
//
#include <hip/hip_runtime.h>
#include <hip/hip_bf16.h>

// ---------------------------------------------------------------------------
// LPGCNHyperConvAblation, round 9: LDS-staged wlp2, all-bf16 stage buffers
// (GEMM A-inputs bf16 via ushort4), fp32 accumulation everywhere.
// ---------------------------------------------------------------------------

__device__ __forceinline__ float ldf(const void* p, int f32, long long i) {
    if (f32) return ((const float*)p)[i];
    unsigned v = ((unsigned)((const unsigned short*)p)[i]) << 16;
    return __uint_as_float(v);
}

__device__ __forceinline__ int ldi(const int* __restrict__ w, int i64, long long i, int lim) {
    int v = i64 ? w[2 * i] : w[i];
    return ((unsigned)v < (unsigned)lim) ? v : 0;
}

__device__ __forceinline__ float b2f(unsigned short u) {
    return __uint_as_float(((unsigned)u) << 16);
}
__device__ __forceinline__ unsigned short f2b(float f) {
    __hip_bfloat16 h = __float2bfloat16(f);
    return *reinterpret_cast<unsigned short*>(&h);
}
__device__ __forceinline__ float4 b2f4(ushort4 u) {
    return make_float4(b2f(u.x), b2f(u.y), b2f(u.z), b2f(u.w));
}
__device__ __forceinline__ ushort4 f2b4(float4 v) {
    ushort4 u; u.x = f2b(v.x); u.y = f2b(v.y); u.z = f2b(v.z); u.w = f2b(v.w);
    return u;
}

// --- fused dtype detection ---------------------------------------------------
struct DPtrs { const void* p[13]; int n[13]; };

__global__ void detect_k(DPtrs dp, int* __restrict__ flags) {
    int b = blockIdx.x;
    __shared__ int cnt;
    if (threadIdx.x == 0) cnt = 0;
    __syncthreads();
    int c = 0;
    if (b < 11) {
        const unsigned short* u = (const unsigned short*)dp.p[b];
        int np = dp.n[b]; if (np > 2048) np = 2048;
        for (int i = threadIdx.x; i < np; i += blockDim.x) {
            unsigned e = (u[i] >> 7) & 0xFFu;
            if (e != 0u && (e < 90u || e > 160u)) c++;
        }
        atomicAdd(&cnt, c);
        __syncthreads();
        if (threadIdx.x == 0) flags[b] = (cnt * 8 > np) ? 1 : 0;
    } else {
        const int* w = (const int*)dp.p[b];
        int np = dp.n[b]; if (np > 1024) np = 1024;
        for (int i = threadIdx.x; i < np; i += blockDim.x)
            if (w[2 * i + 1] != 0) c++;
        atomicAdd(&cnt, c);
        __syncthreads();
        if (threadIdx.x == 0) flags[b] = (cnt == 0) ? 1 : 0;
    }
}

// --- CSR build (atomic-free pipeline) ----------------------------------------
struct Item { int b1; unsigned p1; int b2; unsigned p2; };

__device__ __forceinline__ Item decode(const int* __restrict__ ew, const int* __restrict__ hw,
                                       const int* __restrict__ FL, long long i,
                                       int E, int P, int N, int HE, int shN, int shH) {
    Item it; it.b2 = -1; it.p2 = 0;
    if (i < E) {
        int g = FL[11];
        int key = ldi(ew, g, (long long)E + i, N);
        int val = ldi(ew, g, i, N);
        it.b1 = key >> shN;
        it.p1 = ((unsigned)(key & ((1 << shN) - 1)) << 20) | (unsigned)val;
    } else {
        long long j = i - E;
        int g = FL[12];
        int nd = ldi(hw, g, j, N);
        int he = ldi(hw, g, (long long)P + j, HE);
        it.b1 = 256 + (nd >> shN);
        it.p1 = ((unsigned)(nd & ((1 << shN) - 1)) << 20) | (unsigned)he;
        it.b2 = 512 + (he >> shH);
        it.p2 = ((unsigned)(he & ((1 << shH) - 1)) << 20) | (unsigned)nd;
    }
    return it;
}

__global__ void bucket_count_k(const int* __restrict__ ew, const int* __restrict__ hw,
                               const int* __restrict__ FL, int* __restrict__ gcnt,
                               int E, int P, int N, int HE, int shN, int shH) {
    __shared__ int hist[768];
    int t = threadIdx.x;
    for (int b = t; b < 768; b += 256) hist[b] = 0;
    __syncthreads();
    long long T = (long long)E + P;
    long long stride = (long long)gridDim.x * 256;
    for (long long i = (long long)blockIdx.x * 256 + t; i < T; i += stride) {
        Item it = decode(ew, hw, FL, i, E, P, N, HE, shN, shH);
        atomicAdd(&hist[it.b1], 1);
        if (it.b2 >= 0) atomicAdd(&hist[it.b2], 1);
    }
    __syncthreads();
    for (int b = t; b < 768; b += 256) {
        int h = hist[b];
        if (h) atomicAdd(&gcnt[b], h);
    }
}

__global__ void bucket_scan_k(const int* __restrict__ gcnt, int* __restrict__ bkOff,
                              int* __restrict__ gcur, int E, int P) {
    __shared__ int sh[256];
    int t = threadIdx.x;
    long long rbase[3] = {0, (long long)E, (long long)E + P};
    for (int c = 0; c < 3; c++) {
        int v = gcnt[c * 256 + t];
        sh[t] = v;
        __syncthreads();
        for (int o = 1; o < 256; o <<= 1) {
            int y = (t >= o) ? sh[t - o] : 0;
            __syncthreads();
            sh[t] += y;
            __syncthreads();
        }
        int excl = sh[t] - v;
        bkOff[c * 256 + t] = excl;
        gcur[c * 256 + t] = (int)(rbase[c] + excl);
        __syncthreads();
    }
}

#define PCHUNK 8192

__global__ void bucket_place_k(const int* __restrict__ ew, const int* __restrict__ hw,
                               const int* __restrict__ FL, int* __restrict__ gcur,
                               unsigned* __restrict__ pbuf,
                               int E, int P, int N, int HE, int shN, int shH) {
    __shared__ int hist[768];
    __shared__ int cur[768];
    long long T = (long long)E + P;
    long long start = (long long)blockIdx.x * PCHUNK;
    long long end = start + PCHUNK; if (end > T) end = T;
    int t = threadIdx.x;
    for (int b = t; b < 768; b += 256) hist[b] = 0;
    __syncthreads();
    for (long long i = start + t; i < end; i += 256) {
        Item it = decode(ew, hw, FL, i, E, P, N, HE, shN, shH);
        atomicAdd(&hist[it.b1], 1);
        if (it.b2 >= 0) atomicAdd(&hist[it.b2], 1);
    }
    __syncthreads();
    for (int b = t; b < 768; b += 256) {
        int h = hist[b];
        cur[b] = h ? atomicAdd(&gcur[b], h) : 0;
    }
    __syncthreads();
    for (long long i = start + t; i < end; i += 256) {
        Item it = decode(ew, hw, FL, i, E, P, N, HE, shN, shH);
        int s1 = atomicAdd(&cur[it.b1], 1);
        pbuf[s1] = it.p1;
        if (it.b2 >= 0) {
            int s2 = atomicAdd(&cur[it.b2], 1);
            pbuf[s2] = it.p2;
        }
    }
}

__global__ void build_k(const unsigned* __restrict__ pbuf,
                        const int* __restrict__ gcnt, const int* __restrict__ bkOff,
                        int* __restrict__ eoff, int* __restrict__ ecnt, int* __restrict__ esrc,
                        int* __restrict__ poffN, int* __restrict__ pcntN, int* __restrict__ pheL,
                        int* __restrict__ poffH, int* __restrict__ pcntH, int* __restrict__ pniL,
                        int E, int P, int N, int HE, int shN, int shH) {
    __shared__ int hist[512];
    __shared__ int offs[512];
    __shared__ int s2[256];
    int b = blockIdx.x, t = threadIdx.x;
    int csr = b >> 8, lb = b & 255;
    int sh    = (csr == 2) ? shH : shN;
    int nkeys = (csr == 2) ? HE : N;
    int span = 1 << sh;
    int keyBase = lb << sh;
    if (keyBase >= nkeys) return;
    int keyEnd = keyBase + span; if (keyEnd > nkeys) keyEnd = nkeys;
    int cnt = gcnt[b];
    long long rbase = (csr == 0) ? 0 : ((csr == 1) ? (long long)E : (long long)E + P);
    long long pstart = rbase + bkOff[b];
    int lstBase = bkOff[b];
    int* off  = (csr == 0) ? eoff : ((csr == 1) ? poffN : poffH);
    int* cntA = (csr == 0) ? ecnt : ((csr == 1) ? pcntN : pcntH);
    int* lst  = (csr == 0) ? esrc : ((csr == 1) ? pheL : pniL);

    for (int k = t; k < 512; k += 256) hist[k] = 0;
    __syncthreads();
    for (int i = t; i < cnt; i += 256)
        atomicAdd(&hist[pbuf[pstart + i] >> 20], 1);
    __syncthreads();
    int a0 = hist[2 * t], a1 = hist[2 * t + 1];
    s2[t] = a0 + a1;
    __syncthreads();
    for (int o = 1; o < 256; o <<= 1) {
        int y = (t >= o) ? s2[t - o] : 0;
        __syncthreads();
        s2[t] += y;
        __syncthreads();
    }
    int excl = s2[t] - (a0 + a1);
    offs[2 * t] = excl;
    offs[2 * t + 1] = excl + a0;
    __syncthreads();
    for (int k = keyBase + t; k < keyEnd; k += 256) {
        off[k]  = lstBase + offs[k - keyBase];
        cntA[k] = hist[k - keyBase];
    }
    __syncthreads();
    for (int i = t; i < cnt; i += 256) {
        unsigned u = pbuf[pstart + i];
        int lk = u >> 20;
        int slot = atomicAdd(&offs[lk], 1);
        lst[lstBase + slot] = (int)(u & 0xFFFFFu);
    }
}

// --- fused norm factors ------------------------------------------------------
__global__ void norms_k(const int* __restrict__ ecnt, const int* __restrict__ pcntN,
                        const int* __restrict__ pcntH, float* __restrict__ dis,
                        float* __restrict__ Dinv, float* __restrict__ Binv, int N, int HE) {
    int i = blockIdx.x * blockDim.x + threadIdx.x;
    if (i < N) dis[i] = rsqrtf((float)(ecnt[i] + 1));
    else if (i < 2 * N) { int c = pcntN[i - N]; Dinv[i - N] = c ? (1.f / (float)c) : 0.f; }
    else if (i < 2 * N + HE) { int c = pcntH[i - 2 * N]; Binv[i - 2 * N] = c ? (1.f / (float)c) : 0.f; }
}

// --- Wlp2 = W_c2 @ W_lp, bias2 = b_c2 @ W_lp + b_lp  (LDS-staged) ------------
__global__ void wlp2_k(const void* Wc2, const int* fWc2, const void* Wlp, const int* fWlp,
                       const void* bc2, const int* fbc2, const void* blp, const int* fblp,
                       float* __restrict__ Wlp2, float* __restrict__ bias2, int NC) {
    extern __shared__ float sm[];
    float* sW2 = sm;                 // 64*NC  (W_c2)
    float* sLP = sm + 64 * NC;       // NC*NC  (W_lp)
    int t = threadIdx.x;
    int fw2 = fWc2[0], flp = fWlp[0];
    for (int e = t; e < 64 * NC; e += blockDim.x) sW2[e] = ldf(Wc2, fw2, e);
    for (int e = t; e < NC * NC; e += blockDim.x) sLP[e] = ldf(Wlp, flp, e);
    __syncthreads();
    for (int e = t; e < 64 * NC; e += blockDim.x) {
        int r = e / NC, c = e % NC;
        float s = 0.f;
        for (int k = 0; k < NC; k++) s = fmaf(sW2[r * NC + k], sLP[k * NC + c], s);
        Wlp2[e] = s;
    }
    if (t < NC) {
        float s = ldf(blp, fblp[0], t);
        int fb2 = fbc2[0];
        for (int k = 0; k < NC; k++) s = fmaf(ldf(bc2, fb2, k), sLP[k * NC + t], s);
        bias2[t] = s;
    }
}

// --- bf16 gathers: 4 rows/wave, 16 lanes x ushort4 (D=64) --------------------
__global__ void gat_n2e_k(const ushort4* __restrict__ xw, const int* __restrict__ off,
                          const int* __restrict__ cnt, const int* __restrict__ lst,
                          const float* __restrict__ Binv, ushort4* __restrict__ ef, int HE) {
    int idx = blockIdx.x * blockDim.x + threadIdx.x;
    int e = idx >> 4, l = idx & 15;
    if (e >= HE) return;
    int o = off[e], c = cnt[e];
    float4 a = make_float4(0.f, 0.f, 0.f, 0.f);
    int j = 0;
    for (; j + 4 <= c; j += 4) {
        int s0 = lst[o + j], s1 = lst[o + j + 1], s2 = lst[o + j + 2], s3 = lst[o + j + 3];
        float4 v0 = b2f4(xw[((long long)s0 << 4) + l]);
        float4 v1 = b2f4(xw[((long long)s1 << 4) + l]);
        float4 v2 = b2f4(xw[((long long)s2 << 4) + l]);
        float4 v3 = b2f4(xw[((long long)s3 << 4) + l]);
        a.x += (v0.x + v1.x) + (v2.x + v3.x);
        a.y += (v0.y + v1.y) + (v2.y + v3.y);
        a.z += (v0.z + v1.z) + (v2.z + v3.z);
        a.w += (v0.w + v1.w) + (v2.w + v3.w);
    }
    for (; j < c; j++) {
        float4 v = b2f4(xw[((long long)lst[o + j] << 4) + l]);
        a.x += v.x; a.y += v.y; a.z += v.z; a.w += v.w;
    }
    float bi = Binv[e];
    a.x *= bi; a.y *= bi; a.z *= bi; a.w *= bi;
    ef[((long long)e << 4) + l] = f2b4(a);
}

// hyperedge -> node: out = Dinv*sum + bias (+relu), bf16 out
template <bool RELU>
__global__ void gat_e2n_k(const ushort4* __restrict__ ef, const int* __restrict__ off,
                          const int* __restrict__ cnt, const int* __restrict__ lst,
                          const float* __restrict__ Dinv, const void* __restrict__ bias,
                          const int* __restrict__ fb, ushort4* __restrict__ out, int N) {
    int idx = blockIdx.x * blockDim.x + threadIdx.x;
    int w = idx >> 4, l = idx & 15;
    if (w >= N) return;
    int o = off[w], c = cnt[w];
    float4 a = make_float4(0.f, 0.f, 0.f, 0.f);
    int j = 0;
    for (; j + 4 <= c; j += 4) {
        int s0 = lst[o + j], s1 = lst[o + j + 1], s2 = lst[o + j + 2], s3 = lst[o + j + 3];
        float4 v0 = b2f4(ef[((long long)s0 << 4) + l]);
        float4 v1 = b2f4(ef[((long long)s1 << 4) + l]);
        float4 v2 = b2f4(ef[((long long)s2 << 4) + l]);
        float4 v3 = b2f4(ef[((long long)s3 << 4) + l]);
        a.x += (v0.x + v1.x) + (v2.x + v3.x);
        a.y += (v0.y + v1.y) + (v2.y + v3.y);
        a.z += (v0.z + v1.z) + (v2.z + v3.z);
        a.w += (v0.w + v1.w) + (v2.w + v3.w);
    }
    for (; j < c; j++) {
        float4 v = b2f4(ef[((long long)lst[o + j] << 4) + l]);
        a.x += v.x; a.y += v.y; a.z += v.z; a.w += v.w;
    }
    float di = Dinv[w];
    int fbv = fb[0];
    float4 b = make_float4(ldf(bias, fbv, 4 * l), ldf(bias, fbv, 4 * l + 1),
                           ldf(bias, fbv, 4 * l + 2), ldf(bias, fbv, 4 * l + 3));
    a.x = a.x * di + b.x; a.y = a.y * di + b.y;
    a.z = a.z * di + b.z; a.w = a.w * di + b.w;
    if (RELU) {
        a.x = fmaxf(a.x, 0.f); a.y = fmaxf(a.y, 0.f);
        a.z = fmaxf(a.z, 0.f); a.w = fmaxf(a.w, 0.f);
    }
    out[((long long)w << 4) + l] = f2b4(a);
}

// GCN aggregation on pre-scaled bf16 y, bf16 out
template <bool RELU>
__global__ void gcn_gat_k(const ushort4* __restrict__ y, const int* __restrict__ off,
                          const int* __restrict__ cnt, const int* __restrict__ lst,
                          const float* __restrict__ dis, const void* __restrict__ bias,
                          const int* __restrict__ fb, ushort4* __restrict__ out, int N) {
    int idx = blockIdx.x * blockDim.x + threadIdx.x;
    int w = idx >> 4, l = idx & 15;
    if (w >= N) return;
    int o = off[w], c = cnt[w];
    float4 a = b2f4(y[((long long)w << 4) + l]);
    int j = 0;
    for (; j + 4 <= c; j += 4) {
        int s0 = lst[o + j], s1 = lst[o + j + 1], s2 = lst[o + j + 2], s3 = lst[o + j + 3];
        float4 v0 = b2f4(y[((long long)s0 << 4) + l]);
        float4 v1 = b2f4(y[((long long)s1 << 4) + l]);
        float4 v2 = b2f4(y[((long long)s2 << 4) + l]);
        float4 v3 = b2f4(y[((long long)s3 << 4) + l]);
        a.x += (v0.x + v1.x) + (v2.x + v3.x);
        a.y += (v0.y + v1.y) + (v2.y + v3.y);
        a.z += (v0.z + v1.z) + (v2.z + v3.z);
        a.w += (v0.w + v1.w) + (v2.w + v3.w);
    }
    for (; j < c; j++) {
        float4 v = b2f4(y[((long long)lst[o + j] << 4) + l]);
        a.x += v.x; a.y += v.y; a.z += v.z; a.w += v.w;
    }
    float dd = dis[w];
    int fbv = fb[0];
    float4 b = make_float4(ldf(bias, fbv, 4 * l), ldf(bias, fbv, 4 * l + 1),
                           ldf(bias, fbv, 4 * l + 2), ldf(bias, fbv, 4 * l + 3));
    a.x = a.x * dd + b.x; a.y = a.y * dd + b.y;
    a.z = a.z * dd + b.z; a.w = a.w * dd + b.w;
    if (RELU) {
        a.x = fmaxf(a.x, 0.f); a.y = fmaxf(a.y, 0.f);
        a.z = fmaxf(a.z, 0.f); a.w = fmaxf(a.w, 0.f);
    }
    out[((long long)w << 4) + l] = f2b4(a);
}

// final GCN aggregation over bf16 y2 (M=NC), writes d_out fp32
__global__ void gcn_gatM_k(const ushort4* __restrict__ y2, const int* __restrict__ off,
                           const int* __restrict__ cnt, const int* __restrict__ lst,
                           const float* __restrict__ dis, const float* __restrict__ bias2,
                           float4* __restrict__ out4, int N, int nc4, int npw) {
    int idx = blockIdx.x * blockDim.x + threadIdx.x;
    int wave = idx >> 6, l64 = idx & 63;
    int grp = l64 / 10, li = l64 - grp * 10;
    if (nc4 != 10) { grp = l64 / nc4; li = l64 - grp * nc4; }
    int w = wave * npw + grp;
    if (grp >= npw || w >= N) return;
    int o = off[w], c = cnt[w];
    float4 a = b2f4(y2[(long long)w * nc4 + li]);
    int j = 0;
    for (; j + 4 <= c; j += 4) {
        int s0 = lst[o + j], s1 = lst[o + j + 1], s2 = lst[o + j + 2], s3 = lst[o + j + 3];
        float4 v0 = b2f4(y2[(long long)s0 * nc4 + li]);
        float4 v1 = b2f4(y2[(long long)s1 * nc4 + li]);
        float4 v2 = b2f4(y2[(long long)s2 * nc4 + li]);
        float4 v3 = b2f4(y2[(long long)s3 * nc4 + li]);
        a.x += (v0.x + v1.x) + (v2.x + v3.x);
        a.y += (v0.y + v1.y) + (v2.y + v3.y);
        a.z += (v0.z + v1.z) + (v2.z + v3.z);
        a.w += (v0.w + v1.w) + (v2.w + v3.w);
    }
    for (; j < c; j++) {
        float4 v = b2f4(y2[(long long)lst[o + j] * nc4 + li]);
        a.x += v.x; a.y += v.y; a.z += v.z; a.w += v.w;
    }
    float dd = dis[w];
    float4 b = *(const float4*)&bias2[4 * li];
    a.x = a.x * dd + b.x; a.y = a.y * dd + b.y;
    a.z = a.z * dd + b.z; a.w = a.w * dd + b.w;
    out4[(long long)w * nc4 + li] = a;
}

// --- A-tile loader: fp32/flagged input, or bf16 workspace --------------------
template <bool ABF16>
__device__ __forceinline__ float4 loadA4(const void* A, int af, long long base) {
    if constexpr (ABF16) {
        return b2f4(*(const ushort4*)((const unsigned short*)A + base));
    } else {
        if (af) return *(const float4*)((const float*)A + base);
        float4 v;
        v.x = ldf(A, 0, base); v.y = ldf(A, 0, base + 1);
        v.z = ldf(A, 0, base + 2); v.w = ldf(A, 0, base + 3);
        return v;
    }
}

// --- GEMM: 64x64 tile, 4x4 micro-tile, bf16 out, optional row-scale ----------
template <bool ABF16, bool SCALE>
__global__ __launch_bounds__(256)
void gemm64_k(const void* __restrict__ A, const int* __restrict__ fA,
              const void* __restrict__ B, const int* __restrict__ fB,
              const float* __restrict__ dscale,
              unsigned short* __restrict__ C, int NR, int K, int M) {
    const int af = fA ? fA[0] : 1;
    const int bf = fB ? fB[0] : 1;
    __shared__ float As[16][68];
    __shared__ float Bs[16][68];
    const int t = threadIdx.x;
    const int tx = t & 15, ty = t >> 4;
    const long long m0 = (long long)blockIdx.x * 64;
    float c[4][4] = {};
    for (int k0 = 0; k0 < K; k0 += 16) {
        {
            int row = t >> 2;
            int kk = (t & 3) * 4;
            long long r = m0 + row;
            float4 v = make_float4(0.f, 0.f, 0.f, 0.f);
            if (r < NR) v = loadA4<ABF16>(A, af, r * K + k0 + kk);
            As[kk + 0][row] = v.x; As[kk + 1][row] = v.y;
            As[kk + 2][row] = v.z; As[kk + 3][row] = v.w;
        }
        {
            int krow = t >> 4;
            int nn = (t & 15) * 4;
            int k = k0 + krow;
            float4 v = make_float4(0.f, 0.f, 0.f, 0.f);
            if (nn < M) {
                long long base = (long long)k * M + nn;
                if (bf) v = *(const float4*)((const float*)B + base);
                else {
                    v.x = ldf(B, 0, base); v.y = ldf(B, 0, base + 1);
                    v.z = ldf(B, 0, base + 2); v.w = ldf(B, 0, base + 3);
                }
            }
            *(float4*)&Bs[krow][nn] = v;
        }
        __syncthreads();
#pragma unroll
        for (int k = 0; k < 16; k++) {
            float4 a = *(const float4*)&As[k][ty * 4];
            float4 b = *(const float4*)&Bs[k][tx * 4];
            float av[4] = {a.x, a.y, a.z, a.w};
            float bv[4] = {b.x, b.y, b.z, b.w};
#pragma unroll
            for (int i = 0; i < 4; i++)
#pragma unroll
                for (int j = 0; j < 4; j++) c[i][j] = fmaf(av[i], bv[j], c[i][j]);
        }
        __syncthreads();
    }
    int n = tx * 4;
    if (n < M) {
#pragma unroll
        for (int i = 0; i < 4; i++) {
            long long r = m0 + ty * 4 + i;
            if (r < NR) {
                float s = SCALE ? dscale[r] : 1.f;
                long long o = r * M + n;
                *(ushort4*)&C[o] = f2b4(make_float4(c[i][0] * s, c[i][1] * s,
                                                    c[i][2] * s, c[i][3] * s));
            }
        }
    }
}

// concat GEMM: C = [x | A2(bf16)] @ B, K=192, row-scaled, bf16 out
__global__ __launch_bounds__(256)
void gemm64cat_k(const void* __restrict__ A, const int* __restrict__ fA,
                 const unsigned short* __restrict__ A2,
                 const void* __restrict__ B, const int* __restrict__ fB,
                 const float* __restrict__ dscale,
                 unsigned short* __restrict__ C, int NR, int M) {
    const int af = fA ? fA[0] : 1;
    const int bf = fB ? fB[0] : 1;
    __shared__ float As[16][68];
    __shared__ float Bs[16][68];
    const int t = threadIdx.x;
    const int tx = t & 15, ty = t >> 4;
    const long long m0 = (long long)blockIdx.x * 64;
    float c[4][4] = {};
    for (int k0 = 0; k0 < 192; k0 += 16) {
        {
            int row = t >> 2;
            int kk = (t & 3) * 4;
            long long r = m0 + row;
            float4 v = make_float4(0.f, 0.f, 0.f, 0.f);
            if (r < NR) {
                if (k0 < 128) v = loadA4<false>(A, af, r * 128 + k0 + kk);
                else v = b2f4(*(const ushort4*)&A2[r * 64 + (k0 - 128) + kk]);
            }
            As[kk + 0][row] = v.x; As[kk + 1][row] = v.y;
            As[kk + 2][row] = v.z; As[kk + 3][row] = v.w;
        }
        {
            int krow = t >> 4;
            int nn = (t & 15) * 4;
            int k = k0 + krow;
            float4 v;
            long long base = (long long)k * M + nn;
            if (bf) v = *(const float4*)((const float*)B + base);
            else {
                v.x = ldf(B, 0, base); v.y = ldf(B, 0, base + 1);
                v.z = ldf(B, 0, base + 2); v.w = ldf(B, 0, base + 3);
            }
            *(float4*)&Bs[krow][nn] = v;
        }
        __syncthreads();
#pragma unroll
        for (int k = 0; k < 16; k++) {
            float4 a = *(const float4*)&As[k][ty * 4];
            float4 b = *(const float4*)&Bs[k][tx * 4];
            float av[4] = {a.x, a.y, a.z, a.w};
            float bv[4] = {b.x, b.y, b.z, b.w};
#pragma unroll
            for (int i = 0; i < 4; i++)
#pragma unroll
                for (int j = 0; j < 4; j++) c[i][j] = fmaf(av[i], bv[j], c[i][j]);
        }
        __syncthreads();
    }
    int n = tx * 4;
#pragma unroll
    for (int i = 0; i < 4; i++) {
        long long r = m0 + ty * 4 + i;
        if (r < NR) {
            float s = dscale[r];
            long long o = r * M + n;
            *(ushort4*)&C[o] = f2b4(make_float4(c[i][0] * s, c[i][1] * s,
                                                c[i][2] * s, c[i][3] * s));
        }
    }
}

static inline dim3 g1d(long long n, int b) { return dim3((unsigned)((n + b - 1) / b)); }
static inline int imin(int a, int b) { return a < b ? a : b; }

extern "C" void kernel_launch(void* const* d_in, const int* in_sizes, int n_in,
                              void* d_out, int out_size, void* d_ws, size_t ws_size,
                              hipStream_t stream) {
    const int N  = in_sizes[0] / 128;   // 100000
    const int E  = in_sizes[1] / 2;     // 1600000
    const int P  = in_sizes[2] / 2;     // 800000
    const int HE = 20000;
    const int NC = in_sizes[9] / 64;    // 40
    const int nc4 = NC / 4;             // 10
    const int npw = 64 / nc4;           // 6

    const void* x    = d_in[0];
    const int*  ew   = (const int*)d_in[1];
    const int*  hw   = (const int*)d_in[2];
    const void* W_h1 = d_in[3];
    const void* b_h1 = d_in[4];
    const void* W_h2 = d_in[5];
    const void* b_h2 = d_in[6];
    const void* W_c1 = d_in[7];
    const void* b_c1 = d_in[8];
    const void* W_c2 = d_in[9];
    const void* b_c2 = d_in[10];
    const void* W_lp = d_in[11];
    const void* b_lp = d_in[12];

    int shN = 0; while (((N - 1) >> shN) >= 256) shN++;   // 9
    int shH = 0; while (((HE - 1) >> shH) >= 256) shH++;  // 7

    // ---- workspace ----
    char* wp = (char*)d_ws;
    auto allocF = [&](size_t n) { float* p = (float*)wp; wp += n * 4; return p; };
    auto allocI = [&](size_t n) { int* p = (int*)wp; wp += n * 4; return p; };
    unsigned short* ub  = (unsigned short*)allocF((size_t)N * 32);   // bf16 N*64 (GEMM out)
    unsigned short* hb  = (unsigned short*)allocF((size_t)N * 32);   // bf16 N*64 (gather out)
    unsigned short* efb = (unsigned short*)allocF((size_t)HE * 32);  // bf16 HE*64
    float* dis   = allocF(N);
    float* Dinv  = allocF(N);
    float* Binv  = allocF(HE);
    float* Wlp2  = allocF((size_t)64 * NC);
    float* bias2 = allocF(NC);
    int* ecnt  = allocI(N);
    int* pcntN = allocI(N);
    int* pcntH = allocI(HE);
    int* eoff  = allocI(N);
    int* poffN = allocI(N);
    int* poffH = allocI(HE);
    int* esrc  = allocI(E);
    int* pheL  = allocI(P);
    int* pniL  = allocI(P);
    int* gBkt  = allocI(768);
    int* bkOff = allocI(768);
    int* gcur  = allocI(768);
    int* FL    = allocI(16);
    unsigned* pbuf = (unsigned*)allocI((size_t)E + 2 * (size_t)P);

    dim3 b256(256), d1(1);

    // ---- dtype detection ----
    DPtrs dp;
    const void* farr[11] = {x, W_h1, b_h1, W_h2, b_h2, W_c1, b_c1, W_c2, b_c2, W_lp, b_lp};
    const int   fsz[11]  = {in_sizes[0], in_sizes[3], in_sizes[4], in_sizes[5], in_sizes[6],
                            in_sizes[7], in_sizes[8], in_sizes[9], in_sizes[10], in_sizes[11],
                            in_sizes[12]};
    for (int i = 0; i < 11; ++i) { dp.p[i] = farr[i]; dp.n[i] = fsz[i]; }
    dp.p[11] = ew; dp.n[11] = imin(E, 1024);
    dp.p[12] = hw; dp.n[12] = imin(P, 1024);
    detect_k<<<dim3(13), b256, 0, stream>>>(dp, FL);
    const int* fX   = FL + 0;
    const int* fWh1 = FL + 1,  *fbh1 = FL + 2;
    const int* fWh2 = FL + 3,  *fbh2 = FL + 4;
    const int* fWc1 = FL + 5,  *fbc1 = FL + 6;
    const int* fWc2 = FL + 7,  *fbc2 = FL + 8;
    const int* fWlp = FL + 9,  *fblp = FL + 10;

    // ---- CSR build ----
    hipMemsetAsync(gBkt, 0, 768 * 4, stream);
    bucket_count_k<<<dim3(512), b256, 0, stream>>>(ew, hw, FL, gBkt, E, P, N, HE, shN, shH);
    bucket_scan_k<<<d1, b256, 0, stream>>>(gBkt, bkOff, gcur, E, P);
    {
        long long T = (long long)E + P;
        int nChunks = (int)((T + PCHUNK - 1) / PCHUNK);
        bucket_place_k<<<dim3(nChunks), b256, 0, stream>>>(ew, hw, FL, gcur, pbuf,
                                                           E, P, N, HE, shN, shH);
    }
    build_k<<<dim3(768), b256, 0, stream>>>(pbuf, gBkt, bkOff,
                                            eoff, ecnt, esrc,
                                            poffN, pcntN, pheL,
                                            poffH, pcntH, pniL,
                                            E, P, N, HE, shN, shH);

    // ---- norms + fused tail weights ----
    norms_k<<<g1d(2 * N + HE, 256), b256, 0, stream>>>(ecnt, pcntN, pcntH, dis, Dinv, Binv, N, HE);
    wlp2_k<<<d1, b256, (64 * NC + NC * NC) * 4, stream>>>(
        W_c2, fWc2, W_lp, fWlp, b_c2, fbc2, b_lp, fblp, Wlp2, bias2, NC);

    const dim3 gemmGrid((N + 63) / 64);
    const dim3 gatN16(g1d((long long)N * 16, 256));
    const dim3 gatH16(g1d((long long)HE * 16, 256));
    const dim3 gatNC(g1d((long long)((N + npw - 1) / npw) * 64, 256));

    // ---- hyperconv 1 ----
    gemm64_k<false, false><<<gemmGrid, b256, 0, stream>>>(x, fX, W_h1, fWh1, nullptr, ub, N, 128, 64);
    gat_n2e_k<<<gatH16, b256, 0, stream>>>((const ushort4*)ub, poffH, pcntH, pniL, Binv, (ushort4*)efb, HE);
    gat_e2n_k<true><<<gatN16, b256, 0, stream>>>((const ushort4*)efb, poffN, pcntN, pheL, Dinv, b_h1, fbh1, (ushort4*)hb, N);

    // ---- hyperconv 2 ----
    gemm64_k<true, false><<<gemmGrid, b256, 0, stream>>>(hb, nullptr, W_h2, fWh2, nullptr, ub, N, 64, 64);
    gat_n2e_k<<<gatH16, b256, 0, stream>>>((const ushort4*)ub, poffH, pcntH, pniL, Binv, (ushort4*)efb, HE);
    gat_e2n_k<false><<<gatN16, b256, 0, stream>>>((const ushort4*)efb, poffN, pcntN, pheL, Dinv, b_h2, fbh2, (ushort4*)hb, N);
    // hb = x_hyper (bf16)

    // ---- gcn 1: y = ([x|x_hyper] @ W_c1) * dis (bf16), then gather ----
    gemm64cat_k<<<gemmGrid, b256, 0, stream>>>(x, fX, hb, W_c1, fWc1, dis, ub, N, 64);
    gcn_gat_k<true><<<gatN16, b256, 0, stream>>>((const ushort4*)ub, eoff, ecnt, esrc, dis, b_c1, fbc1, (ushort4*)hb, N);

    // ---- gcn 2 + final linear fused: y2 = (hb @ Wlp2) * dis (bf16), gather ----
    gemm64_k<true, true><<<gemmGrid, b256, 0, stream>>>(hb, nullptr, Wlp2, nullptr, dis, ub, N, 64, NC);
    gcn_gatM_k<<<gatNC, b256, 0, stream>>>((const ushort4*)ub, eoff, ecnt, esrc, dis, bias2, (float4*)d_out, N, nc4, npw);
}